// Round 5
// baseline (427.244 us; speedup 1.0000x reference)
//
#include <hip/hip_runtime.h>
#include <math.h>

#define N 4096
#define ROUNDS 12           // round 0 (folded) + 11: components at least halve per hook
#define INFKEY 0xFFFFFFFFFFFFFFFFULL
#define LCAP 64             // candidate-list capacity per row == wave width
#define EC (N - 1)          // MST edge count
#define M2 (2 * EC)         // directed edges (8190)
#define MBLK 32             // blocks per matrix (known-good operating point)
#define RPB (N / MBLK)      // 128 rows per block
#define RPW (RPB / 16)      // 8 rows per wave

typedef unsigned long long u64;
typedef unsigned int u32;
typedef unsigned short u16;
typedef unsigned char u8;

// ---- workspace layout (bytes) ----
#define WS_PARENT(ws) ((int*)((char*)(ws) + 0))          // int[2N]        32 KB
#define WS_RCNT(ws)   ((int*)((char*)(ws) + 32768))      // int[2N]        32 KB
#define WS_RTHR(ws)   ((float*)((char*)(ws) + 65536))    // float[2N]      32 KB
#define WS_EDGES(ws)  ((int2*)((char*)(ws) + 98304))     // int2[2N]       64 KB
#define WS_CAND(ws)   ((u64*)((char*)(ws) + 163840))     // u64[2][2N]    128 KB (double-buffered)
#define WS_META(ws)   ((int*)((char*)(ws) + 294912))     // int[64]
#define WS_LISTS(ws)  ((u64*)((char*)(ws) + 295168))     // u64[2N*LCAP]    4 MB, row-major

// cand key: (float_bits(w) << 24) | (u << 12) | v    (56 bits)
// list entry: (float_bits(w) << 12) | j              (44 bits)

// Per-matrix spin barrier over MBLK co-resident blocks (grid 64 on 256 CUs).
__device__ __forceinline__ void mat_barrier(int* cnt, int* gen, int target) {
    __syncthreads();
    if (threadIdx.x == 0) {
        __threadfence();
        int old = atomicAdd(cnt, 1);
        if (old == MBLK - 1) {
            __hip_atomic_store(cnt, 0, __ATOMIC_RELAXED, __HIP_MEMORY_SCOPE_AGENT);
            __hip_atomic_store(gen, target, __ATOMIC_RELEASE, __HIP_MEMORY_SCOPE_AGENT);
        } else {
            while (__hip_atomic_load(gen, __ATOMIC_ACQUIRE, __HIP_MEMORY_SCOPE_AGENT) < target)
                __builtin_amdgcn_s_sleep(1);
        }
        __threadfence();
    }
    __syncthreads();
}

// Tiny init: meta counters + cand buffer 1. Must run before solve (the spin
// barrier and round-1 candidate buffer need these pre-set). ~3 us.
__global__ __launch_bounds__(1024) void init_kernel(u64* __restrict__ cand,
                                                    int* __restrict__ meta) {
    const int tid = threadIdx.x;
#pragma unroll
    for (int j = 0; j < 8; ++j)
        cand[2 * N + tid * 8 + j] = INFKEY;
    if (tid < 64) meta[tid] = 0;
}

// FUSED kernel. Stage 0 (build): each block streams its own 128 rows
// (wave-per-row, 8 sequential rows/wave, 4-float4 batches -> no 64-VGPR row
// pinning). Count/emit passes re-read the row: per XCD ~8 blocks x 16 waves
// x 16KB = 2MB live rows <= 4MB L2, so re-reads are L2 hits. The separate
// build kernel was ~140 us invariant to 3 different shapes and never showed
// in top-5 counters; fusing makes the whole pipeline one visible dispatch.
// Then rounds as before: A (list scan) -> barrier -> B (bound filter +
// rescans) -> barrier -> C (redundant hook+compress). Euler-tour rooting by
// leader blocks; block 0 fuses finalize. MBLK=32 known-good (128 regressed).
__global__ __launch_bounds__(1024) void solve_kernel(const float* __restrict__ D1,
                                                     const float* __restrict__ D2,
                                                     int* __restrict__ rcnt,
                                                     float* __restrict__ rthr,
                                                     u64* __restrict__ lists,
                                                     u64* __restrict__ cand_g,
                                                     int2* __restrict__ edges_g,
                                                     int* __restrict__ parent_g,
                                                     int* __restrict__ meta,
                                                     float* __restrict__ out) {
    const int b = blockIdx.x;
    const int m = b / MBLK;
    const int bm = b - m * MBLK;
    const int tid = threadIdx.x;
    const int wid = tid >> 6, lane = tid & 63;
    const float* __restrict__ D = m ? D2 : D1;
    int* __restrict__ grc = rcnt + m * N;
    float* __restrict__ gth = rthr + m * N;
    u64* __restrict__ gls = lists + (size_t)m * N * LCAP;
    int2* __restrict__ ged = edges_g + (size_t)m * N;
    int* __restrict__ gpar = parent_g + m * N;
    int* bcnt = meta + m * 16 + 1;
    int* bgen = meta + m * 16 + 2;
    int* garr = meta + 40;                 // global arrive counter (all 64 blocks)
    const float INF = __builtin_inff();

    __shared__ __align__(16) char SM[57344];   // 56 KB arena, phase-aliased
    int* scomp = (int*)SM;                     // 16 KB @0   (private full comp)
    u64* scand = (u64*)(SM + 16384);           // 32 KB @16K (local min mirror / staged cand)
    u16* sresc = (u16*)(SM + 49152);           // 8 KB  @48K (rescan list / slink)
    __shared__ u8 sexh[RPB];                   // monotone exhausted-row flags
    __shared__ int snres, secnt, scnt, swar[16];

    for (int i = tid; i < N; i += 1024) scomp[i] = i;
    for (int i = tid; i < RPB; i += 1024) sexh[i] = 0;
    if (tid == 0) secnt = 0;
    int phase = 0;
    bool done = false;

    // ================= stage 0: build own 128 rows =================
    for (int r8 = 0; r8 < RPW; ++r8) {
        const int lrow = wid * RPW + r8;
        const int row = bm * RPB + lrow;
        const float* __restrict__ Drow = D + (size_t)row * N;

        // pass 1: row-min KEY + sum (streaming, 4 float4 in flight)
        u64 kmin = INFKEY;
        float sm = 0.f;
        for (int it4 = 0; it4 < 4; ++it4) {
            float4 vv[4];
#pragma unroll
            for (int j = 0; j < 4; ++j)
                vv[j] = *(const float4*)(Drow + (it4 * 4 + j) * 256 + lane * 4);
#pragma unroll
            for (int j = 0; j < 4; ++j) {
                const int base = (it4 * 4 + j) * 256 + lane * 4;
                float e4[4] = {vv[j].x, vv[j].y, vv[j].z, vv[j].w};
#pragma unroll
                for (int s = 0; s < 4; ++s) {
                    float x = e4[s];
                    if (x > 0.f) {   // excludes exact-zero diagonal
                        u64 k = ((u64)__float_as_uint(x) << 12) | (unsigned)(base + s);
                        if (k < kmin) kmin = k;
                    }
                    sm += x;         // self adds 0, harmless
                }
            }
        }
#pragma unroll
        for (int off = 32; off > 0; off >>= 1) {
            u64 o = __shfl_xor(kmin, off, 64);
            if (o < kmin) kmin = o;
            sm += __shfl_xor(sm, off, 64);
        }
        const float mn = __uint_as_float((u32)(kmin >> 12));
        const float mean = sm * (1.f / 4095.f);
        float T = mn + 0.25f * (mean - mn);

        // adaptive threshold: halve gap until ball count <= LCAP (re-reads L2-hot)
        int mycnt = 0, total = 0;
        for (int iter = 0; iter < 10; ++iter) {
            mycnt = 0;
            for (int it4 = 0; it4 < 4; ++it4) {
                float4 vv[4];
#pragma unroll
                for (int j = 0; j < 4; ++j)
                    vv[j] = *(const float4*)(Drow + (it4 * 4 + j) * 256 + lane * 4);
#pragma unroll
                for (int j = 0; j < 4; ++j) {
                    mycnt += (vv[j].x > 0.f && vv[j].x < T);
                    mycnt += (vv[j].y > 0.f && vv[j].y < T);
                    mycnt += (vv[j].z > 0.f && vv[j].z < T);
                    mycnt += (vv[j].w > 0.f && vv[j].w < T);
                }
            }
            total = mycnt;
#pragma unroll
            for (int off = 32; off > 0; off >>= 1) total += __shfl_xor(total, off, 64);
            if (total <= LCAP) break;        // wave-uniform
            T = mn + 0.5f * (T - mn);
        }

        // exclusive scan of final per-lane counts -> emit positions
        int incl = mycnt;
#pragma unroll
        for (int d = 1; d < 64; d <<= 1) {
            int o = __shfl_up(incl, d, 64);
            if (lane >= d) incl += o;
        }
        int pos = incl - mycnt;

        u64* lp = gls + (size_t)row * LCAP;   // ROW-major
        for (int it4 = 0; it4 < 4; ++it4) {
            float4 vv[4];
#pragma unroll
            for (int j = 0; j < 4; ++j)
                vv[j] = *(const float4*)(Drow + (it4 * 4 + j) * 256 + lane * 4);
#pragma unroll
            for (int j = 0; j < 4; ++j) {
                const int base = (it4 * 4 + j) * 256 + lane * 4;
                float e4[4] = {vv[j].x, vv[j].y, vv[j].z, vv[j].w};
#pragma unroll
                for (int s = 0; s < 4; ++s) {
                    float x = e4[s];
                    if (x > 0.f && x < T) {
                        if (pos < LCAP)
                            lp[pos] = ((u64)__float_as_uint(x) << 12) | (unsigned)(base + s);
                        ++pos;
                    }
                }
            }
        }
        if (lane == 0) {
            grc[row] = total;
            gth[row] = T;
            // Boruvka round-1 candidate (cand buffer 0), unique writer per row
            cand_g[(size_t)m * N + row] = ((kmin >> 12) << 24) | ((u64)row << 12) | (kmin & 0xFFF);
        }
    }
    mat_barrier(bcnt, bgen, ++phase);   // stage 0 -> rounds (cand/lists visible)

    // ================= Boruvka rounds =================
    for (int round = 0; round < ROUNDS && !done; ++round) {
        const int buf = round & 1;
        u64* __restrict__ gcand = cand_g + (size_t)buf * 2 * N + m * N;

        if (round > 0) {
            u64* __restrict__ gcand_o = cand_g + (size_t)(buf ^ 1) * 2 * N + m * N;
            for (int i = tid; i < N; i += 1024) scand[i] = INFKEY;
            if (tid == 0) snres = 0;
            __syncthreads();

            // ---- phase A: prefetched list scan; exhausted rows skip ----
            {
                const int lbase = wid * RPW;
                int cnts[RPW];
                u64 ent[RPW];
#pragma unroll
                for (int r = 0; r < RPW; ++r) {
                    int lrow = lbase + r;
                    cnts[r] = sexh[lrow] ? -1 : grc[bm * RPB + lrow];   // uniform scalar load
                }
#pragma unroll
                for (int r = 0; r < RPW; ++r) {   // 8 independent global loads in flight
                    int lrow = lbase + r;
                    ent[r] = (cnts[r] > lane) ? gls[(size_t)(bm * RPB + lrow) * LCAP + lane]
                                              : INFKEY;
                }
#pragma unroll
                for (int r = 0; r < RPW; ++r) {
                    const int lrow = lbase + r;
                    const int row = bm * RPB + lrow;
                    if (cnts[r] < 0) {                       // known exhausted
                        if (lane == 0) { int i = atomicAdd(&snres, 1); sresc[i] = (u16)(row | 0x1000); }
                        continue;
                    }
                    if (cnts[r] > LCAP) {                    // defensive overflow
                        if (lane == 0) { int i = atomicAdd(&snres, 1); sresc[i] = (u16)(row | 0x4000); }
                        continue;
                    }
                    const int c = scomp[row];
                    u64 e = ent[r];
                    u64 best = (e != INFKEY && scomp[(int)(e & 0xFFF)] != c) ? e : INFKEY;
#pragma unroll
                    for (int off = 32; off > 0; off >>= 1) {
                        u64 o = __shfl_xor(best, off, 64);
                        if (o < best) best = o;
                    }
                    if (lane == 0) {
                        if (best != INFKEY) {
                            u64 key = ((best >> 12) << 24) | ((u64)row << 12) | (best & 0xFFF);
                            if (key < scand[c]) atomicMin(&scand[c], key);
                        } else {
                            sexh[lrow] = 1;                  // permanent (monotone)
                            int i = atomicAdd(&snres, 1); sresc[i] = (u16)(row | 0x1000);
                        }
                    }
                }
            }
            __syncthreads();
            for (int c = tid; c < N; c += 1024) {            // flush block-local mins
                u64 v = scand[c];
                if (v != INFKEY) atomicMin(&gcand[c], v);
            }
            mat_barrier(bcnt, bgen, ++phase);   // A -> B

            // ---- phase B: reset idle buffer slice; bound filter; rare rescans ----
            if (tid < RPB)
                __hip_atomic_store(&gcand_o[bm * RPB + tid], INFKEY,
                                   __ATOMIC_RELAXED, __HIP_MEMORY_SCOPE_AGENT);
            for (int i = tid; i < snres; i += 1024) {
                u16 e = sresc[i];
                if (e & 0x1000) {
                    int row = e & 0xFFF;
                    int c = scomp[row];
                    u64 cc = gcand[c];           // monotone-decreasing: skip stays safe
                    float w = (cc == INFKEY) ? INF : __uint_as_float((u32)(cc >> 24));
                    if (!(gth[row] < w)) sresc[i] = 0xFFFF;
                }
            }
            __syncthreads();
            {
                const int nres = snres;
                for (int i = wid; i < nres; i += 16) {
                    u16 e = sresc[i];            // wave-uniform broadcast
                    if (e == 0xFFFF) continue;
                    int row = (int)(e & 0xFFF);
                    int c = scomp[row];
                    const float* Drow = D + (size_t)row * N;
                    u64 best = INFKEY;
                    for (int j0 = lane * 4; j0 < N; j0 += 256) {
                        float4 d = *(const float4*)(Drow + j0);
                        int4 cj = *(const int4*)(scomp + j0);
                        if (cj.x != c) { u64 k = ((u64)__float_as_uint(d.x) << 12) | (unsigned)(j0 + 0); if (k < best) best = k; }
                        if (cj.y != c) { u64 k = ((u64)__float_as_uint(d.y) << 12) | (unsigned)(j0 + 1); if (k < best) best = k; }
                        if (cj.z != c) { u64 k = ((u64)__float_as_uint(d.z) << 12) | (unsigned)(j0 + 2); if (k < best) best = k; }
                        if (cj.w != c) { u64 k = ((u64)__float_as_uint(d.w) << 12) | (unsigned)(j0 + 3); if (k < best) best = k; }
                    }
#pragma unroll
                    for (int off = 32; off > 0; off >>= 1) {
                        u64 o = __shfl_xor(best, off, 64);
                        if (o < best) best = o;
                    }
                    if (lane == 0 && best != INFKEY) {
                        u64 key = ((best >> 12) << 24) | ((u64)row << 12) | (best & 0xFFF);
                        atomicMin(&gcand[c], key);
                    }
                }
            }
            mat_barrier(bcnt, bgen, ++phase);   // B -> C
        }

        // ---- phase C (all blocks, redundant+deterministic): stage cand, hook,
        //      record edges (block 0 only), compress, done check ----
        for (int i = tid; i < N; i += 1024) scand[i] = gcand[i];   // quiescent
        __syncthreads();
        u16* slink = sresc;
        for (int c = tid; c < N; c += 1024) {
            int l = scomp[c];
            if (l == c) {
                u64 k = scand[c];
                if (k != INFKEY) {
                    int v = (int)(k & 0xFFF);
                    int u = (int)((k >> 12) & 0xFFF);
                    int t = scomp[v];
                    u64 tk = scand[t];
                    int mutual = 0;
                    if (tk != INFKEY) {
                        int tv = (int)(tk & 0xFFF);
                        mutual = (scomp[tv] == c);
                    }
                    if (mutual) {
                        if (c < t) {
                            if (bm == 0) { int idx = atomicAdd(&secnt, 1); ged[idx] = make_int2(u, v); }
                        } else l = t;
                    } else {
                        if (bm == 0) { int idx = atomicAdd(&secnt, 1); ged[idx] = make_int2(u, v); }
                        l = t;
                    }
                }
            }
            slink[c] = (u16)l;
        }
        __syncthreads();
        for (int c = tid; c < N; c += 1024) scomp[c] = slink[c];
        __syncthreads();
        for (int c = tid; c < N; c += 1024) {   // concurrent root-walk (monotone)
            int r = scomp[c];
            int n = scomp[r];
            while (n != r) { r = n; n = scomp[r]; }
            scomp[c] = r;
        }
        __syncthreads();
        if (tid == 0) scnt = 0;
        __syncthreads();
        int local = 0;
        for (int c = tid; c < N; c += 1024) local += (scomp[c] == c) ? 1 : 0;
        atomicAdd(&scnt, local);
        __syncthreads();
        done = (scnt == 1);                  // identical across blocks
        __syncthreads();
    }

    if (bm == 0) {
        // ============ Euler-tour rooting (leader block, depth-independent) =====
        u32* uvp  = (u32*)SM;                      // 16K @0
        u16* off  = (u16*)(SM + 16384);            // 8K
        u16* adj  = (u16*)(SM + 24576);            // 16K
        u16* succ = (u16*)(SM + 40960);            // 16K
        u16* rnk  = (u16*)(SM + 16384);            // aliases off+adj (dead)
        u32* minp = (u32*)(SM + 40960);            // aliases succ (dead)

        __syncthreads();
        const int ec = secnt;                      // == N-1
        for (int i = tid; i < ec; i += 1024) {
            int2 e = ged[i];
            uvp[i] = ((u32)e.x << 16) | (u32)e.y;
        }
        for (int i = tid; i < 2048; i += 1024) ((u32*)off)[i] = 0;
        __syncthreads();
        for (int i = tid; i < ec; i += 1024) {
            u32 w = uvp[i];
            int u = (int)(w >> 16), v = (int)(w & 0xFFFF);
            atomicAdd((u32*)off + (u >> 1), 1u << ((u & 1) * 16));
            atomicAdd((u32*)off + (v >> 1), 1u << ((v & 1) * 16));
        }
        __syncthreads();
        {
            const int i0 = tid * 4;
            int d0 = off[i0], d1 = off[i0 + 1], d2 = off[i0 + 2], d3 = off[i0 + 3];
            int t0 = d0, t01 = d0 + d1, t012 = t01 + d2, tot = t012 + d3;
            int inc = tot;
#pragma unroll
            for (int d = 1; d < 64; d <<= 1) {
                int o = __shfl_up(inc, d, 64);
                if (lane >= d) inc += o;
            }
            if (lane == 63) swar[wid] = inc;
            __syncthreads();
            if (wid == 0) {
                int v = (lane < 16) ? swar[lane] : 0;
                int vin = v;
#pragma unroll
                for (int d = 1; d < 16; d <<= 1) {
                    int o = __shfl_up(v, d, 64);
                    if (lane >= d) v += o;
                }
                if (lane < 16) swar[lane] = v - vin;
            }
            __syncthreads();
            int base = swar[wid] + (inc - tot);
            off[i0] = (u16)base;
            off[i0 + 1] = (u16)(base + t0);
            off[i0 + 2] = (u16)(base + t01);
            off[i0 + 3] = (u16)(base + t012);
        }
        __syncthreads();
        for (int e = tid; e < M2; e += 1024) {
            int i = e >> 1;
            u32 w = uvp[i];
            int src = (e & 1) ? (int)(w & 0xFFFF) : (int)(w >> 16);
            u32 old = atomicAdd((u32*)off + (src >> 1), 1u << ((src & 1) * 16));
            u32 slot = (old >> ((src & 1) * 16)) & 0xFFFFu;
            adj[slot] = (u16)e;
            succ[e] = (u16)slot;                 // temp: my slot
        }
        __syncthreads();
        const int e0 = adj[0];                   // first edge out of vertex 0 = tour start
        {
            u16 nsv[8];
            int k = 0;
            for (int e = tid; e < M2; e += 1024) {
                int i = e >> 1;
                u32 w = uvp[i];
                int v = (e & 1) ? (int)(w >> 16) : (int)(w & 0xFFFF);   // dst(e)
                int st = succ[e ^ 1];
                int start = (v == 0) ? 0 : off[v - 1];
                int end = off[v];
                int ns = (st + 1 < end) ? st + 1 : start;
                nsv[k++] = adj[ns];
            }
            __syncthreads();
            k = 0;
            for (int e = tid; e < M2; e += 1024) succ[e] = nsv[k++];
        }
        __syncthreads();
        for (int e = tid; e < M2; e += 1024) {
            u16 s = succ[e];
            if (s == (u16)e0) { succ[e] = (u16)e; rnk[e] = 0; }
            else rnk[e] = 1;
        }
        __syncthreads();
        for (int it = 0; it < 13; ++it) {
            u16 nr[8], s2[8];
            int k = 0;
            for (int e = tid; e < M2; e += 1024) {
                u16 s1 = succ[e];
                u16 r1 = rnk[e];
                nr[k] = (u16)(r1 + rnk[s1]);
                s2[k] = succ[s1];
                ++k;
            }
            __syncthreads();
            k = 0;
            for (int e = tid; e < M2; e += 1024) { rnk[e] = nr[k]; succ[e] = s2[k]; ++k; }
            __syncthreads();
        }
        for (int i = tid; i < N; i += 1024) minp[i] = 0xFFFFFFFFu;
        __syncthreads();
        for (int e = tid; e < M2; e += 1024) {
            int i = e >> 1;
            u32 w = uvp[i];
            int dst = (e & 1) ? (int)(w >> 16) : (int)(w & 0xFFFF);
            int srcv = (e & 1) ? (int)(w & 0xFFFF) : (int)(w >> 16);
            u32 p = (u32)(M2 - 1) - (u32)rnk[e];
            atomicMin(&minp[dst], (p << 16) | (u32)srcv);
        }
        __syncthreads();
        for (int v = tid; v < N; v += 1024) gpar[v] = (v == 0) ? 0 : (int)(minp[v] & 0xFFFFu);
    }

    // ---- global arrive; block 0 waits for all 64, then computes outputs ----
    __syncthreads();
    if (tid == 0) {
        __threadfence();
        atomicAdd(garr, 1);
    }
    if (b != 0) return;
    if (tid == 0) {
        while (__hip_atomic_load(garr, __ATOMIC_ACQUIRE, __HIP_MEMORY_SCOPE_AGENT) < 2 * MBLK)
            __builtin_amdgcn_s_sleep(1);
        __threadfence();
    }
    __syncthreads();

    // fused finalize (block 0 only)
    {
        float* rs12 = (float*)SM;            // tiny scratch
        float* rs21 = (float*)(SM + 64);
        int* rm = (int*)(SM + 128);
        const int* p1 = parent_g;
        const int* p2 = parent_g + N;
        float s12 = 0.f, s21 = 0.f;
        int mcnt = 0;
        for (int c = 1 + tid; c < N; c += 1024) {
            int a = p1[c];
            int bb = p2[c];
            float e1 = D1[(size_t)a * N + c] - D2[(size_t)a * N + c];
            float e2 = D2[(size_t)bb * N + c] - D1[(size_t)bb * N + c];
            s12 += e1 * e1;
            s21 += e2 * e2;
            mcnt += (a == bb) ? 1 : 0;
        }
#pragma unroll
        for (int off = 32; off > 0; off >>= 1) {
            s12 += __shfl_xor(s12, off, 64);
            s21 += __shfl_xor(s21, off, 64);
            mcnt += __shfl_xor(mcnt, off, 64);
        }
        if (lane == 0) { rs12[wid] = s12; rs21[wid] = s21; rm[wid] = mcnt; }
        __syncthreads();
        if (tid == 0) {
            float a = 0.f, bb = 0.f;
            int mm = 0;
#pragma unroll
            for (int w = 0; w < 16; ++w) { a += rs12[w]; bb += rs21[w]; mm += rm[w]; }
            float d12 = sqrtf(a);
            float d21 = sqrtf(bb);
            out[0] = d12 + d21;
            out[1] = d12;
            out[2] = d21;
            out[3] = (float)mm;
        }
    }
}

extern "C" void kernel_launch(void* const* d_in, const int* in_sizes, int n_in,
                              void* d_out, int out_size, void* d_ws, size_t ws_size,
                              hipStream_t stream) {
    const float* D1 = (const float*)d_in[0];
    const float* D2 = (const float*)d_in[1];

    int* parent = WS_PARENT(d_ws);
    int* rcnt = WS_RCNT(d_ws);
    float* rthr = WS_RTHR(d_ws);
    int2* edges = WS_EDGES(d_ws);
    u64* cand = WS_CAND(d_ws);
    int* meta = WS_META(d_ws);
    u64* lists = WS_LISTS(d_ws);

    init_kernel<<<1, 1024, 0, stream>>>(cand, meta);
    solve_kernel<<<2 * MBLK, 1024, 0, stream>>>(D1, D2, rcnt, rthr, lists, cand,
                                                edges, parent, meta, (float*)d_out);
}

// Round 6
// 289.893 us; speedup vs baseline: 1.4738x; 1.4738x over previous
//
#include <hip/hip_runtime.h>
#include <math.h>

#define N 4096
#define ROUNDS 12           // round 0 (folded) + 11: components at least halve per hook
#define INFKEY 0xFFFFFFFFFFFFFFFFULL
#define LCAP 64             // candidate-list capacity per row == wave width
#define EC (N - 1)          // MST edge count
#define M2 (2 * EC)         // directed edges (8190)
#define MBLK 32             // blocks per matrix (known-good operating point)
#define RPB (N / MBLK)      // 128 rows per block
#define RPW (RPB / 16)      // 8 rows per wave

typedef unsigned long long u64;
typedef unsigned int u32;
typedef unsigned short u16;
typedef unsigned char u8;

// ---- workspace layout (bytes) ----
#define WS_PARENT(ws) ((int*)((char*)(ws) + 0))          // int[2N]        32 KB
#define WS_RCNT(ws)   ((int*)((char*)(ws) + 32768))      // int[2N]        32 KB
#define WS_RTHR(ws)   ((float*)((char*)(ws) + 65536))    // float[2N]      32 KB
#define WS_EDGES(ws)  ((int2*)((char*)(ws) + 98304))     // int2[2N]       64 KB
#define WS_CAND(ws)   ((u64*)((char*)(ws) + 163840))     // u64[2][2N]    128 KB (double-buffered)
#define WS_META(ws)   ((int*)((char*)(ws) + 294912))     // int[64]
#define WS_LISTS(ws)  ((u64*)((char*)(ws) + 295168))     // u64[2N*LCAP]    4 MB, row-major

// cand key: (float_bits(w) << 24) | (u << 12) | v    (56 bits)
// list entry: (float_bits(w) << 12) | j              (44 bits)

// Per-matrix spin barrier over MBLK co-resident blocks (grid 64 on 256 CUs).
__device__ __forceinline__ void mat_barrier(int* cnt, int* gen, int target) {
    __syncthreads();
    if (threadIdx.x == 0) {
        __threadfence();
        int old = atomicAdd(cnt, 1);
        if (old == MBLK - 1) {
            __hip_atomic_store(cnt, 0, __ATOMIC_RELAXED, __HIP_MEMORY_SCOPE_AGENT);
            __hip_atomic_store(gen, target, __ATOMIC_RELEASE, __HIP_MEMORY_SCOPE_AGENT);
        } else {
            while (__hip_atomic_load(gen, __ATOMIC_ACQUIRE, __HIP_MEMORY_SCOPE_AGENT) < target)
                __builtin_amdgcn_s_sleep(1);
        }
        __threadfence();
    }
    __syncthreads();
}

// One 256-thread BLOCK per row (grid 8192). ~40 us actual (corrected for the
// ~100 us fixed harness gap discovered in round 5); HBM floor ~21 us.
// Semantics: row-min KEY -> cand buffer 0; adaptive ball threshold T (gap
// halved until count <= LCAP); complete ROW-major ball list.
__global__ __launch_bounds__(256) void build_kernel(const float* __restrict__ D1,
                                                    const float* __restrict__ D2,
                                                    int* __restrict__ rowcount,
                                                    float* __restrict__ rthresh,
                                                    u64* __restrict__ lists,
                                                    u64* __restrict__ cand,
                                                    int* __restrict__ meta) {
    const int gb = blockIdx.x;   // 8192 blocks: one per (matrix,row)
    const int tid = threadIdx.x;
    const int wid = tid >> 6, lane = tid & 63;

    // folded init: only cand buffer 1 (buffer 0 is fully written below) + meta
    if (gb < 8) {
        int i = 2 * N + (gb * 256 + tid) * 4;
        cand[i] = INFKEY; cand[i + 1] = INFKEY; cand[i + 2] = INFKEY; cand[i + 3] = INFKEY;
    } else if (gb == 8 && tid < 64) {
        meta[tid] = 0;
    }

    const int m = gb >> 12;
    const int row = gb & (N - 1);
    const float* __restrict__ Drow = (m ? D2 : D1) + (size_t)row * N;

    __shared__ u64 skmin[4];
    __shared__ float ssum[4];
    __shared__ int scnt4[4];

    float4 v[4];
#pragma unroll
    for (int it = 0; it < 4; ++it)
        v[it] = *(const float4*)(Drow + it * 1024 + tid * 4);

    // per-thread min KEY + sum over 16 elems, then wave reduce, then LDS combine
    u64 kmin = INFKEY;
    float sm = 0.f;
#pragma unroll
    for (int it = 0; it < 4; ++it) {
        float e4[4] = {v[it].x, v[it].y, v[it].z, v[it].w};
#pragma unroll
        for (int s = 0; s < 4; ++s) {
            float x = e4[s];
            if (x > 0.f) {   // excludes exact-zero diagonal
                u64 k = ((u64)__float_as_uint(x) << 12) | (unsigned)(it * 1024 + tid * 4 + s);
                if (k < kmin) kmin = k;
            }
            sm += x;         // self adds 0, harmless
        }
    }
#pragma unroll
    for (int off = 32; off > 0; off >>= 1) {
        u64 o = __shfl_xor(kmin, off, 64);
        if (o < kmin) kmin = o;
        sm += __shfl_xor(sm, off, 64);
    }
    if (lane == 0) { skmin[wid] = kmin; ssum[wid] = sm; }
    __syncthreads();
    kmin = skmin[0]; sm = ssum[0];
#pragma unroll
    for (int w = 1; w < 4; ++w) {
        if (skmin[w] < kmin) kmin = skmin[w];
        sm += ssum[w];
    }
    const float mn = __uint_as_float((u32)(kmin >> 12));
    const float mean = sm * (1.f / 4095.f);
    float T = mn + 0.25f * (mean - mn);   // block-uniform: identical inputs everywhere

    int mycnt, total;
    for (int iter = 0; iter < 10; ++iter) {
        mycnt = 0;
#pragma unroll
        for (int it = 0; it < 4; ++it) {
            mycnt += (v[it].x > 0.f && v[it].x < T);
            mycnt += (v[it].y > 0.f && v[it].y < T);
            mycnt += (v[it].z > 0.f && v[it].z < T);
            mycnt += (v[it].w > 0.f && v[it].w < T);
        }
        int t = mycnt;
#pragma unroll
        for (int off = 32; off > 0; off >>= 1) t += __shfl_xor(t, off, 64);
        if (lane == 0) scnt4[wid] = t;
        __syncthreads();
        total = scnt4[0] + scnt4[1] + scnt4[2] + scnt4[3];   // block-uniform
        if (total <= LCAP) break;            // uniform break: no barrier divergence
        T = mn + 0.5f * (T - mn);
        __syncthreads();                     // protect scnt4 for next iter's write
    }
    __syncthreads();                         // protect scnt4 reuse below

    // exclusive prefix across 256 threads: wave scan + 4-entry wave-offset scan
    int incl = mycnt;
#pragma unroll
    for (int d = 1; d < 64; d <<= 1) {
        int o = __shfl_up(incl, d, 64);
        if (lane >= d) incl += o;
    }
    if (lane == 63) scnt4[wid] = incl;
    __syncthreads();
    int wbase = 0;
#pragma unroll
    for (int w = 0; w < 4; ++w)
        if (w < wid) wbase += scnt4[w];
    int pos = wbase + incl - mycnt;

    u64* lp = lists + ((size_t)m * N + row) * LCAP;   // ROW-major
#pragma unroll
    for (int it = 0; it < 4; ++it) {
        float e4[4] = {v[it].x, v[it].y, v[it].z, v[it].w};
#pragma unroll
        for (int s = 0; s < 4; ++s) {
            float x = e4[s];
            if (x > 0.f && x < T) {
                if (pos < LCAP)
                    lp[pos] = ((u64)__float_as_uint(x) << 12) | (unsigned)(it * 1024 + tid * 4 + s);
                ++pos;
            }
        }
    }
    if (tid == 0) {
        rowcount[m * N + row] = total;
        rthresh[m * N + row] = T;
        // Boruvka round-1 candidate: every vertex its own component, unique writer
        cand[m * N + row] = ((kmin >> 12) << 24) | ((u64)row << 12) | (kmin & 0xFFF);
    }
}

// 32 blocks per matrix (64 total). Round 0 = hook only. Rounds 1+:
// A (list scan) -> barrier -> B (bound filter + rare rescans) -> barrier ->
// C (redundant deterministic hook+compress). This revision trims phase C from
// 5 N-loops to 3: u16 double-buffered comp array (cur/nxt swap kills the
// slink->scomp copy), root-count fused into the walk with per-round sdone
// slots (kills the count pass + 2 syncs), uint4-vectorized gcand staging.
__global__ __launch_bounds__(1024) void solve_kernel(const float* __restrict__ D1,
                                                     const float* __restrict__ D2,
                                                     const int* __restrict__ rcnt,
                                                     const float* __restrict__ rthr,
                                                     const u64* __restrict__ lists,
                                                     u64* __restrict__ cand_g,
                                                     int2* __restrict__ edges_g,
                                                     int* __restrict__ parent_g,
                                                     int* __restrict__ meta,
                                                     float* __restrict__ out) {
    const int b = blockIdx.x;
    const int m = b / MBLK;
    const int bm = b - m * MBLK;
    const int tid = threadIdx.x;
    const int wid = tid >> 6, lane = tid & 63;
    const float* __restrict__ D = m ? D2 : D1;
    const int* __restrict__ grc = rcnt + m * N;
    const float* __restrict__ gth = rthr + m * N;
    const u64* __restrict__ gls = lists + (size_t)m * N * LCAP;
    int2* __restrict__ ged = edges_g + (size_t)m * N;
    int* __restrict__ gpar = parent_g + m * N;
    int* bcnt = meta + m * 16 + 1;
    int* bgen = meta + m * 16 + 2;
    int* garr = meta + 40;                 // global arrive counter (all 64 blocks)
    const float INF = __builtin_inff();

    __shared__ __align__(16) char SM[57344];   // 56 KB arena, phase-aliased
    u16* comp0 = (u16*)SM;                     // 8 KB @0    (component buffer A)
    u16* comp1 = (u16*)(SM + 8192);            // 8 KB @8K   (component buffer B)
    u64* scand = (u64*)(SM + 16384);           // 32 KB @16K (local min mirror / staged cand)
    u16* sresc = (u16*)(SM + 49152);           // 8 KB  @48K (rescan list)
    __shared__ u8 sexh[RPB];                   // monotone exhausted-row flags
    __shared__ int snres, secnt, sdone[ROUNDS], swar[16];

    u16* cur = comp0;                          // swapped identically in all threads
    u16* nxt = comp1;

    for (int i = tid; i < N; i += 1024) cur[i] = (u16)i;
    for (int i = tid; i < RPB; i += 1024) sexh[i] = 0;
    if (tid == 0) secnt = 0;
    if (tid < ROUNDS) sdone[tid] = 0;
    int phase = 0;
    bool done = false;

    for (int round = 0; round < ROUNDS && !done; ++round) {
        const int buf = round & 1;
        u64* __restrict__ gcand = cand_g + (size_t)buf * 2 * N + m * N;

        if (round > 0) {
            u64* __restrict__ gcand_o = cand_g + (size_t)(buf ^ 1) * 2 * N + m * N;
            for (int i = tid; i < N; i += 1024) scand[i] = INFKEY;
            if (tid == 0) snres = 0;
            __syncthreads();

            // ---- phase A: prefetched list scan; exhausted rows skip ----
            {
                const int lbase = wid * RPW;
                int cnts[RPW];
                u64 ent[RPW];
#pragma unroll
                for (int r = 0; r < RPW; ++r) {
                    int lrow = lbase + r;
                    cnts[r] = sexh[lrow] ? -1 : grc[bm * RPB + lrow];   // uniform scalar load
                }
#pragma unroll
                for (int r = 0; r < RPW; ++r) {   // 8 independent global loads in flight
                    int lrow = lbase + r;
                    ent[r] = (cnts[r] > lane) ? gls[(size_t)(bm * RPB + lrow) * LCAP + lane]
                                              : INFKEY;
                }
#pragma unroll
                for (int r = 0; r < RPW; ++r) {
                    const int lrow = lbase + r;
                    const int row = bm * RPB + lrow;
                    if (cnts[r] < 0) {                       // known exhausted
                        if (lane == 0) { int i = atomicAdd(&snres, 1); sresc[i] = (u16)(row | 0x1000); }
                        continue;
                    }
                    if (cnts[r] > LCAP) {                    // defensive overflow
                        if (lane == 0) { int i = atomicAdd(&snres, 1); sresc[i] = (u16)(row | 0x4000); }
                        continue;
                    }
                    const int c = cur[row];
                    u64 e = ent[r];
                    u64 best = (e != INFKEY && cur[(int)(e & 0xFFF)] != c) ? e : INFKEY;
#pragma unroll
                    for (int off = 32; off > 0; off >>= 1) {
                        u64 o = __shfl_xor(best, off, 64);
                        if (o < best) best = o;
                    }
                    if (lane == 0) {
                        if (best != INFKEY) {
                            u64 key = ((best >> 12) << 24) | ((u64)row << 12) | (best & 0xFFF);
                            if (key < scand[c]) atomicMin(&scand[c], key);
                        } else {
                            sexh[lrow] = 1;                  // permanent (monotone)
                            int i = atomicAdd(&snres, 1); sresc[i] = (u16)(row | 0x1000);
                        }
                    }
                }
            }
            __syncthreads();
            for (int c = tid; c < N; c += 1024) {            // flush block-local mins
                u64 v = scand[c];
                if (v != INFKEY) atomicMin(&gcand[c], v);
            }
            mat_barrier(bcnt, bgen, ++phase);   // A -> B

            // ---- phase B: reset idle buffer slice; bound filter; rare rescans ----
            if (tid < RPB)
                __hip_atomic_store(&gcand_o[bm * RPB + tid], INFKEY,
                                   __ATOMIC_RELAXED, __HIP_MEMORY_SCOPE_AGENT);
            for (int i = tid; i < snres; i += 1024) {
                u16 e = sresc[i];
                if (e & 0x1000) {
                    int row = e & 0xFFF;
                    int c = cur[row];
                    u64 cc = gcand[c];           // monotone-decreasing: skip stays safe
                    float w = (cc == INFKEY) ? INF : __uint_as_float((u32)(cc >> 24));
                    if (!(gth[row] < w)) sresc[i] = 0xFFFF;
                }
            }
            __syncthreads();
            {
                const int nres = snres;
                for (int i = wid; i < nres; i += 16) {
                    u16 e = sresc[i];            // wave-uniform broadcast
                    if (e == 0xFFFF) continue;
                    int row = (int)(e & 0xFFF);
                    int c = cur[row];
                    const float* Drow = D + (size_t)row * N;
                    u64 best = INFKEY;
                    for (int j0 = lane * 4; j0 < N; j0 += 256) {
                        float4 d = *(const float4*)(Drow + j0);
                        ushort4 cj = *(const ushort4*)(cur + j0);
                        if (cj.x != c) { u64 k = ((u64)__float_as_uint(d.x) << 12) | (unsigned)(j0 + 0); if (k < best) best = k; }
                        if (cj.y != c) { u64 k = ((u64)__float_as_uint(d.y) << 12) | (unsigned)(j0 + 1); if (k < best) best = k; }
                        if (cj.z != c) { u64 k = ((u64)__float_as_uint(d.z) << 12) | (unsigned)(j0 + 2); if (k < best) best = k; }
                        if (cj.w != c) { u64 k = ((u64)__float_as_uint(d.w) << 12) | (unsigned)(j0 + 3); if (k < best) best = k; }
                    }
#pragma unroll
                    for (int off = 32; off > 0; off >>= 1) {
                        u64 o = __shfl_xor(best, off, 64);
                        if (o < best) best = o;
                    }
                    if (lane == 0 && best != INFKEY) {
                        u64 key = ((best >> 12) << 24) | ((u64)row << 12) | (best & 0xFFF);
                        atomicMin(&gcand[c], key);
                    }
                }
            }
            mat_barrier(bcnt, bgen, ++phase);   // B -> C
        }

        // ---- phase C (all blocks, redundant+deterministic): stage cand, hook
        //      into nxt, walk+count fused, swap buffers ----
        for (int i = tid; i < N / 2; i += 1024)             // 16B vector staging
            ((uint4*)scand)[i] = ((const uint4*)gcand)[i];  // quiescent
        __syncthreads();
        for (int c = tid; c < N; c += 1024) {
            int l = cur[c];
            if (l == c) {
                u64 k = scand[c];
                if (k != INFKEY) {
                    int v = (int)(k & 0xFFF);
                    int u = (int)((k >> 12) & 0xFFF);
                    int t = cur[v];
                    u64 tk = scand[t];
                    int mutual = 0;
                    if (tk != INFKEY) {
                        int tv = (int)(tk & 0xFFF);
                        mutual = (cur[tv] == c);
                    }
                    if (mutual) {
                        if (c < t) {
                            if (bm == 0) { int idx = atomicAdd(&secnt, 1); ged[idx] = make_int2(u, v); }
                        } else l = t;
                    } else {
                        if (bm == 0) { int idx = atomicAdd(&secnt, 1); ged[idx] = make_int2(u, v); }
                        l = t;
                    }
                }
            }
            nxt[c] = (u16)l;
        }
        __syncthreads();
        int local = 0;
        for (int c = tid; c < N; c += 1024) {   // concurrent root-walk (monotone) + count
            int r = nxt[c];
            int n = nxt[r];
            while (n != r) { r = n; n = nxt[r]; }
            nxt[c] = (u16)r;
            local += (r == c) ? 1 : 0;
        }
        atomicAdd(&sdone[round], local);
        __syncthreads();
        done = (sdone[round] == 1);             // identical across blocks
        { u16* tmp = cur; cur = nxt; nxt = tmp; }
    }

    if (bm == 0) {
        // ============ Euler-tour rooting (leader block, depth-independent) =====
        u32* uvp  = (u32*)SM;                      // 16K @0 (comp buffers dead)
        u16* off  = (u16*)(SM + 16384);            // 8K
        u16* adj  = (u16*)(SM + 24576);            // 16K
        u16* succ = (u16*)(SM + 40960);            // 16K
        u16* rnk  = (u16*)(SM + 16384);            // aliases off+adj (dead)
        u32* minp = (u32*)(SM + 40960);            // aliases succ (dead)

        __syncthreads();
        const int ec = secnt;                      // == N-1
        for (int i = tid; i < ec; i += 1024) {
            int2 e = ged[i];
            uvp[i] = ((u32)e.x << 16) | (u32)e.y;
        }
        for (int i = tid; i < 2048; i += 1024) ((u32*)off)[i] = 0;
        __syncthreads();
        for (int i = tid; i < ec; i += 1024) {
            u32 w = uvp[i];
            int u = (int)(w >> 16), v = (int)(w & 0xFFFF);
            atomicAdd((u32*)off + (u >> 1), 1u << ((u & 1) * 16));
            atomicAdd((u32*)off + (v >> 1), 1u << ((v & 1) * 16));
        }
        __syncthreads();
        {
            const int i0 = tid * 4;
            int d0 = off[i0], d1 = off[i0 + 1], d2 = off[i0 + 2], d3 = off[i0 + 3];
            int t0 = d0, t01 = d0 + d1, t012 = t01 + d2, tot = t012 + d3;
            int inc = tot;
#pragma unroll
            for (int d = 1; d < 64; d <<= 1) {
                int o = __shfl_up(inc, d, 64);
                if (lane >= d) inc += o;
            }
            if (lane == 63) swar[wid] = inc;
            __syncthreads();
            if (wid == 0) {
                int v = (lane < 16) ? swar[lane] : 0;
                int vin = v;
#pragma unroll
                for (int d = 1; d < 16; d <<= 1) {
                    int o = __shfl_up(v, d, 64);
                    if (lane >= d) v += o;
                }
                if (lane < 16) swar[lane] = v - vin;
            }
            __syncthreads();
            int base = swar[wid] + (inc - tot);
            off[i0] = (u16)base;
            off[i0 + 1] = (u16)(base + t0);
            off[i0 + 2] = (u16)(base + t01);
            off[i0 + 3] = (u16)(base + t012);
        }
        __syncthreads();
        for (int e = tid; e < M2; e += 1024) {
            int i = e >> 1;
            u32 w = uvp[i];
            int src = (e & 1) ? (int)(w & 0xFFFF) : (int)(w >> 16);
            u32 old = atomicAdd((u32*)off + (src >> 1), 1u << ((src & 1) * 16));
            u32 slot = (old >> ((src & 1) * 16)) & 0xFFFFu;
            adj[slot] = (u16)e;
            succ[e] = (u16)slot;                 // temp: my slot
        }
        __syncthreads();
        const int e0 = adj[0];                   // first edge out of vertex 0 = tour start
        {
            u16 nsv[8];
            int k = 0;
            for (int e = tid; e < M2; e += 1024) {
                int i = e >> 1;
                u32 w = uvp[i];
                int v = (e & 1) ? (int)(w >> 16) : (int)(w & 0xFFFF);   // dst(e)
                int st = succ[e ^ 1];
                int start = (v == 0) ? 0 : off[v - 1];
                int end = off[v];
                int ns = (st + 1 < end) ? st + 1 : start;
                nsv[k++] = adj[ns];
            }
            __syncthreads();
            k = 0;
            for (int e = tid; e < M2; e += 1024) succ[e] = nsv[k++];
        }
        __syncthreads();
        for (int e = tid; e < M2; e += 1024) {
            u16 s = succ[e];
            if (s == (u16)e0) { succ[e] = (u16)e; rnk[e] = 0; }
            else rnk[e] = 1;
        }
        __syncthreads();
        for (int it = 0; it < 13; ++it) {
            u16 nr[8], s2[8];
            int k = 0;
            for (int e = tid; e < M2; e += 1024) {
                u16 s1 = succ[e];
                u16 r1 = rnk[e];
                nr[k] = (u16)(r1 + rnk[s1]);
                s2[k] = succ[s1];
                ++k;
            }
            __syncthreads();
            k = 0;
            for (int e = tid; e < M2; e += 1024) { rnk[e] = nr[k]; succ[e] = s2[k]; ++k; }
            __syncthreads();
        }
        for (int i = tid; i < N; i += 1024) minp[i] = 0xFFFFFFFFu;
        __syncthreads();
        for (int e = tid; e < M2; e += 1024) {
            int i = e >> 1;
            u32 w = uvp[i];
            int dst = (e & 1) ? (int)(w >> 16) : (int)(w & 0xFFFF);
            int srcv = (e & 1) ? (int)(w & 0xFFFF) : (int)(w >> 16);
            u32 p = (u32)(M2 - 1) - (u32)rnk[e];
            atomicMin(&minp[dst], (p << 16) | (u32)srcv);
        }
        __syncthreads();
        for (int v = tid; v < N; v += 1024) gpar[v] = (v == 0) ? 0 : (int)(minp[v] & 0xFFFFu);
    }

    // ---- global arrive; block 0 waits for all 64, then computes outputs ----
    __syncthreads();
    if (tid == 0) {
        __threadfence();
        atomicAdd(garr, 1);
    }
    if (b != 0) return;
    if (tid == 0) {
        while (__hip_atomic_load(garr, __ATOMIC_ACQUIRE, __HIP_MEMORY_SCOPE_AGENT) < 2 * MBLK)
            __builtin_amdgcn_s_sleep(1);
        __threadfence();
    }
    __syncthreads();

    // fused finalize (block 0 only)
    {
        float* rs12 = (float*)SM;            // tiny scratch
        float* rs21 = (float*)(SM + 64);
        int* rm = (int*)(SM + 128);
        const int* p1 = parent_g;
        const int* p2 = parent_g + N;
        float s12 = 0.f, s21 = 0.f;
        int mcnt = 0;
        for (int c = 1 + tid; c < N; c += 1024) {
            int a = p1[c];
            int bb = p2[c];
            float e1 = D1[(size_t)a * N + c] - D2[(size_t)a * N + c];
            float e2 = D2[(size_t)bb * N + c] - D1[(size_t)bb * N + c];
            s12 += e1 * e1;
            s21 += e2 * e2;
            mcnt += (a == bb) ? 1 : 0;
        }
#pragma unroll
        for (int off = 32; off > 0; off >>= 1) {
            s12 += __shfl_xor(s12, off, 64);
            s21 += __shfl_xor(s21, off, 64);
            mcnt += __shfl_xor(mcnt, off, 64);
        }
        if (lane == 0) { rs12[wid] = s12; rs21[wid] = s21; rm[wid] = mcnt; }
        __syncthreads();
        if (tid == 0) {
            float a = 0.f, bb = 0.f;
            int mm = 0;
#pragma unroll
            for (int w = 0; w < 16; ++w) { a += rs12[w]; bb += rs21[w]; mm += rm[w]; }
            float d12 = sqrtf(a);
            float d21 = sqrtf(bb);
            out[0] = d12 + d21;
            out[1] = d12;
            out[2] = d21;
            out[3] = (float)mm;
        }
    }
}

extern "C" void kernel_launch(void* const* d_in, const int* in_sizes, int n_in,
                              void* d_out, int out_size, void* d_ws, size_t ws_size,
                              hipStream_t stream) {
    const float* D1 = (const float*)d_in[0];
    const float* D2 = (const float*)d_in[1];

    int* parent = WS_PARENT(d_ws);
    int* rcnt = WS_RCNT(d_ws);
    float* rthr = WS_RTHR(d_ws);
    int2* edges = WS_EDGES(d_ws);
    u64* cand = WS_CAND(d_ws);
    int* meta = WS_META(d_ws);
    u64* lists = WS_LISTS(d_ws);

    build_kernel<<<2 * N, 256, 0, stream>>>(D1, D2, rcnt, rthr, lists, cand, meta);
    solve_kernel<<<2 * MBLK, 1024, 0, stream>>>(D1, D2, rcnt, rthr, lists, cand,
                                                edges, parent, meta, (float*)d_out);
}

// Round 7
// 276.406 us; speedup vs baseline: 1.5457x; 1.0488x over previous
//
#include <hip/hip_runtime.h>
#include <math.h>

#define N 4096
#define ROUNDS 12           // round 0 (folded) + 11: components at least halve per hook
#define INFKEY 0xFFFFFFFFFFFFFFFFULL
#define LCAP 64             // candidate-list capacity per row == wave width
#define EC (N - 1)          // MST edge count
#define M2 (2 * EC)         // directed edges (8190)
#define MBLK 32             // blocks per matrix (known-good operating point)
#define RPB (N / MBLK)      // 128 rows per block
#define RPW (RPB / 16)      // 8 rows per wave

typedef unsigned long long u64;
typedef unsigned int u32;
typedef unsigned short u16;
typedef unsigned char u8;

// ---- workspace layout (bytes) ----
#define WS_PARENT(ws) ((int*)((char*)(ws) + 0))          // int[2N]        32 KB
#define WS_RCNT(ws)   ((int*)((char*)(ws) + 32768))      // int[2N]        32 KB
#define WS_RTHR(ws)   ((float*)((char*)(ws) + 65536))    // float[2N]      32 KB
#define WS_EDGES(ws)  ((int2*)((char*)(ws) + 98304))     // int2[2N]       64 KB
#define WS_CAND(ws)   ((u64*)((char*)(ws) + 163840))     // u64[2][2N]    128 KB (double-buffered)
#define WS_META(ws)   ((int*)((char*)(ws) + 294912))     // int[64]
#define WS_LISTS(ws)  ((u64*)((char*)(ws) + 295168))     // u64[2N*LCAP]    4 MB, row-major

// cand key (TAGGED): ((ROUNDS-round) << 56) | (float_bits(w) << 24) | (u << 12) | v
//   Tags strictly decrease per round -> fresh keys always win atomicMin vs
//   stale same-buffer keys from round-2 ago; phase C validates tag instead of
//   INFKEY. This removes the per-round idle-buffer reset, which was the only
//   hard ordering constraint the A->B barrier protected -> 1 barrier/round.
// list entry: (float_bits(w) << 12) | j              (44 bits)

// Per-matrix spin barrier over MBLK co-resident blocks (grid 64 on 256 CUs).
__device__ __forceinline__ void mat_barrier(int* cnt, int* gen, int target) {
    __syncthreads();
    if (threadIdx.x == 0) {
        __threadfence();
        int old = atomicAdd(cnt, 1);
        if (old == MBLK - 1) {
            __hip_atomic_store(cnt, 0, __ATOMIC_RELAXED, __HIP_MEMORY_SCOPE_AGENT);
            __hip_atomic_store(gen, target, __ATOMIC_RELEASE, __HIP_MEMORY_SCOPE_AGENT);
        } else {
            while (__hip_atomic_load(gen, __ATOMIC_ACQUIRE, __HIP_MEMORY_SCOPE_AGENT) < target)
                __builtin_amdgcn_s_sleep(1);
        }
        __threadfence();
    }
    __syncthreads();
}

// One 256-thread BLOCK per row (grid 8192). ~40 us actual (corrected for the
// ~100 us fixed harness gap discovered in round 5); HBM floor ~21 us.
// Semantics: row-min KEY -> cand buffer 0 (tag ROUNDS); adaptive ball
// threshold T (gap halved until count <= LCAP); complete ROW-major ball list.
__global__ __launch_bounds__(256) void build_kernel(const float* __restrict__ D1,
                                                    const float* __restrict__ D2,
                                                    int* __restrict__ rowcount,
                                                    float* __restrict__ rthresh,
                                                    u64* __restrict__ lists,
                                                    u64* __restrict__ cand,
                                                    int* __restrict__ meta) {
    const int gb = blockIdx.x;   // 8192 blocks: one per (matrix,row)
    const int tid = threadIdx.x;
    const int wid = tid >> 6, lane = tid & 63;

    // folded init: cand buffer 1 (buffer 0 is fully written below) + meta
    if (gb < 8) {
        int i = 2 * N + (gb * 256 + tid) * 4;
        cand[i] = INFKEY; cand[i + 1] = INFKEY; cand[i + 2] = INFKEY; cand[i + 3] = INFKEY;
    } else if (gb == 8 && tid < 64) {
        meta[tid] = 0;
    }

    const int m = gb >> 12;
    const int row = gb & (N - 1);
    const float* __restrict__ Drow = (m ? D2 : D1) + (size_t)row * N;

    __shared__ u64 skmin[4];
    __shared__ float ssum[4];
    __shared__ int scnt4[4];

    float4 v[4];
#pragma unroll
    for (int it = 0; it < 4; ++it)
        v[it] = *(const float4*)(Drow + it * 1024 + tid * 4);

    // per-thread min KEY + sum over 16 elems, then wave reduce, then LDS combine
    u64 kmin = INFKEY;
    float sm = 0.f;
#pragma unroll
    for (int it = 0; it < 4; ++it) {
        float e4[4] = {v[it].x, v[it].y, v[it].z, v[it].w};
#pragma unroll
        for (int s = 0; s < 4; ++s) {
            float x = e4[s];
            if (x > 0.f) {   // excludes exact-zero diagonal
                u64 k = ((u64)__float_as_uint(x) << 12) | (unsigned)(it * 1024 + tid * 4 + s);
                if (k < kmin) kmin = k;
            }
            sm += x;         // self adds 0, harmless
        }
    }
#pragma unroll
    for (int off = 32; off > 0; off >>= 1) {
        u64 o = __shfl_xor(kmin, off, 64);
        if (o < kmin) kmin = o;
        sm += __shfl_xor(sm, off, 64);
    }
    if (lane == 0) { skmin[wid] = kmin; ssum[wid] = sm; }
    __syncthreads();
    kmin = skmin[0]; sm = ssum[0];
#pragma unroll
    for (int w = 1; w < 4; ++w) {
        if (skmin[w] < kmin) kmin = skmin[w];
        sm += ssum[w];
    }
    const float mn = __uint_as_float((u32)(kmin >> 12));
    const float mean = sm * (1.f / 4095.f);
    float T = mn + 0.25f * (mean - mn);   // block-uniform: identical inputs everywhere

    int mycnt, total;
    for (int iter = 0; iter < 10; ++iter) {
        mycnt = 0;
#pragma unroll
        for (int it = 0; it < 4; ++it) {
            mycnt += (v[it].x > 0.f && v[it].x < T);
            mycnt += (v[it].y > 0.f && v[it].y < T);
            mycnt += (v[it].z > 0.f && v[it].z < T);
            mycnt += (v[it].w > 0.f && v[it].w < T);
        }
        int t = mycnt;
#pragma unroll
        for (int off = 32; off > 0; off >>= 1) t += __shfl_xor(t, off, 64);
        if (lane == 0) scnt4[wid] = t;
        __syncthreads();
        total = scnt4[0] + scnt4[1] + scnt4[2] + scnt4[3];   // block-uniform
        if (total <= LCAP) break;            // uniform break: no barrier divergence
        T = mn + 0.5f * (T - mn);
        __syncthreads();                     // protect scnt4 for next iter's write
    }
    __syncthreads();                         // protect scnt4 reuse below

    // exclusive prefix across 256 threads: wave scan + 4-entry wave-offset scan
    int incl = mycnt;
#pragma unroll
    for (int d = 1; d < 64; d <<= 1) {
        int o = __shfl_up(incl, d, 64);
        if (lane >= d) incl += o;
    }
    if (lane == 63) scnt4[wid] = incl;
    __syncthreads();
    int wbase = 0;
#pragma unroll
    for (int w = 0; w < 4; ++w)
        if (w < wid) wbase += scnt4[w];
    int pos = wbase + incl - mycnt;

    u64* lp = lists + ((size_t)m * N + row) * LCAP;   // ROW-major
#pragma unroll
    for (int it = 0; it < 4; ++it) {
        float e4[4] = {v[it].x, v[it].y, v[it].z, v[it].w};
#pragma unroll
        for (int s = 0; s < 4; ++s) {
            float x = e4[s];
            if (x > 0.f && x < T) {
                if (pos < LCAP)
                    lp[pos] = ((u64)__float_as_uint(x) << 12) | (unsigned)(it * 1024 + tid * 4 + s);
                ++pos;
            }
        }
    }
    if (tid == 0) {
        rowcount[m * N + row] = total;
        rthresh[m * N + row] = T;
        // Boruvka round-0 candidate, tag = ROUNDS, unique writer per row
        cand[m * N + row] = ((u64)ROUNDS << 56) | ((kmin >> 12) << 24) | ((u64)row << 12) | (kmin & 0xFFF);
    }
}

// 32 blocks per matrix (64 total). Round 0 = hook only. Rounds 1+:
// A (list scan + flush) -> B (bound filter + rare rescans, NO barrier before)
// -> mat_barrier -> C (redundant deterministic hook+compress). The A->B
// barrier is gone: tag-validated keys make the idle-buffer reset unnecessary
// (its only hard ordering need), and the bound filter is monotone-safe under
// partial gcand visibility (stale/partial -> conservative rescan).
__global__ __launch_bounds__(1024) void solve_kernel(const float* __restrict__ D1,
                                                     const float* __restrict__ D2,
                                                     const int* __restrict__ rcnt,
                                                     const float* __restrict__ rthr,
                                                     const u64* __restrict__ lists,
                                                     u64* __restrict__ cand_g,
                                                     int2* __restrict__ edges_g,
                                                     int* __restrict__ parent_g,
                                                     int* __restrict__ meta,
                                                     float* __restrict__ out) {
    const int b = blockIdx.x;
    const int m = b / MBLK;
    const int bm = b - m * MBLK;
    const int tid = threadIdx.x;
    const int wid = tid >> 6, lane = tid & 63;
    const float* __restrict__ D = m ? D2 : D1;
    const int* __restrict__ grc = rcnt + m * N;
    const float* __restrict__ gth = rthr + m * N;
    const u64* __restrict__ gls = lists + (size_t)m * N * LCAP;
    int2* __restrict__ ged = edges_g + (size_t)m * N;
    int* __restrict__ gpar = parent_g + m * N;
    int* bcnt = meta + m * 16 + 1;
    int* bgen = meta + m * 16 + 2;
    int* garr = meta + 40;                 // global arrive counter (all 64 blocks)
    const float INF = __builtin_inff();

    __shared__ __align__(16) char SM[57344];   // 56 KB arena, phase-aliased
    u16* comp0 = (u16*)SM;                     // 8 KB @0    (component buffer A)
    u16* comp1 = (u16*)(SM + 8192);            // 8 KB @8K   (component buffer B)
    u64* scand = (u64*)(SM + 16384);           // 32 KB @16K (local min mirror / staged cand)
    u16* sresc = (u16*)(SM + 49152);           // 8 KB  @48K (rescan list)
    __shared__ u8 sexh[RPB];                   // monotone exhausted-row flags
    __shared__ int snres, secnt, sdone[ROUNDS], swar[16];

    u16* cur = comp0;                          // swapped identically in all threads
    u16* nxt = comp1;

    for (int i = tid; i < N; i += 1024) cur[i] = (u16)i;
    for (int i = tid; i < RPB; i += 1024) sexh[i] = 0;
    if (tid == 0) secnt = 0;
    if (tid < ROUNDS) sdone[tid] = 0;
    int phase = 0;
    bool done = false;

    for (int round = 0; round < ROUNDS && !done; ++round) {
        const int buf = round & 1;
        const u64 tg = (u64)(ROUNDS - round);          // this round's tag
        const u64 tgs = tg << 56;
        u64* __restrict__ gcand = cand_g + (size_t)buf * 2 * N + m * N;

        if (round > 0) {
            for (int i = tid; i < N; i += 1024) scand[i] = INFKEY;
            if (tid == 0) snres = 0;
            __syncthreads();

            // ---- phase A: prefetched list scan; exhausted rows skip ----
            {
                const int lbase = wid * RPW;
                int cnts[RPW];
                u64 ent[RPW];
#pragma unroll
                for (int r = 0; r < RPW; ++r) {
                    int lrow = lbase + r;
                    cnts[r] = sexh[lrow] ? -1 : grc[bm * RPB + lrow];   // uniform scalar load
                }
#pragma unroll
                for (int r = 0; r < RPW; ++r) {   // 8 independent global loads in flight
                    int lrow = lbase + r;
                    ent[r] = (cnts[r] > lane) ? gls[(size_t)(bm * RPB + lrow) * LCAP + lane]
                                              : INFKEY;
                }
#pragma unroll
                for (int r = 0; r < RPW; ++r) {
                    const int lrow = lbase + r;
                    const int row = bm * RPB + lrow;
                    if (cnts[r] < 0) {                       // known exhausted
                        if (lane == 0) { int i = atomicAdd(&snres, 1); sresc[i] = (u16)(row | 0x1000); }
                        continue;
                    }
                    if (cnts[r] > LCAP) {                    // defensive overflow
                        if (lane == 0) { int i = atomicAdd(&snres, 1); sresc[i] = (u16)(row | 0x4000); }
                        continue;
                    }
                    const int c = cur[row];
                    u64 e = ent[r];
                    u64 best = (e != INFKEY && cur[(int)(e & 0xFFF)] != c) ? e : INFKEY;
#pragma unroll
                    for (int off = 32; off > 0; off >>= 1) {
                        u64 o = __shfl_xor(best, off, 64);
                        if (o < best) best = o;
                    }
                    if (lane == 0) {
                        if (best != INFKEY) {
                            u64 key = tgs | ((best >> 12) << 24) | ((u64)row << 12) | (best & 0xFFF);
                            if (key < scand[c]) atomicMin(&scand[c], key);
                        } else {
                            sexh[lrow] = 1;                  // permanent (monotone)
                            int i = atomicAdd(&snres, 1); sresc[i] = (u16)(row | 0x1000);
                        }
                    }
                }
            }
            __syncthreads();
            for (int c = tid; c < N; c += 1024) {            // flush block-local mins
                u64 v = scand[c];
                if (v != INFKEY) atomicMin(&gcand[c], v);
            }
            __syncthreads();                 // own flushes visible to own filter reads

            // ---- phase B (no preceding barrier): bound filter; rare rescans ----
            for (int i = tid; i < snres; i += 1024) {
                u16 e = sresc[i];
                if (e & 0x1000) {
                    int row = e & 0xFFF;
                    int c = cur[row];
                    u64 cc = gcand[c];           // partial/monotone: skip stays safe
                    float w = ((cc >> 56) == tg) ? __uint_as_float((u32)(cc >> 24)) : INF;
                    if (!(gth[row] < w)) sresc[i] = 0xFFFF;
                }
            }
            __syncthreads();
            {
                const int nres = snres;
                for (int i = wid; i < nres; i += 16) {
                    u16 e = sresc[i];            // wave-uniform broadcast
                    if (e == 0xFFFF) continue;
                    int row = (int)(e & 0xFFF);
                    int c = cur[row];
                    const float* Drow = D + (size_t)row * N;
                    u64 best = INFKEY;
                    for (int j0 = lane * 4; j0 < N; j0 += 256) {
                        float4 d = *(const float4*)(Drow + j0);
                        ushort4 cj = *(const ushort4*)(cur + j0);
                        if (cj.x != c) { u64 k = ((u64)__float_as_uint(d.x) << 12) | (unsigned)(j0 + 0); if (k < best) best = k; }
                        if (cj.y != c) { u64 k = ((u64)__float_as_uint(d.y) << 12) | (unsigned)(j0 + 1); if (k < best) best = k; }
                        if (cj.z != c) { u64 k = ((u64)__float_as_uint(d.z) << 12) | (unsigned)(j0 + 2); if (k < best) best = k; }
                        if (cj.w != c) { u64 k = ((u64)__float_as_uint(d.w) << 12) | (unsigned)(j0 + 3); if (k < best) best = k; }
                    }
#pragma unroll
                    for (int off = 32; off > 0; off >>= 1) {
                        u64 o = __shfl_xor(best, off, 64);
                        if (o < best) best = o;
                    }
                    if (lane == 0 && best != INFKEY) {
                        u64 key = tgs | ((best >> 12) << 24) | ((u64)row << 12) | (best & 0xFFF);
                        atomicMin(&gcand[c], key);
                    }
                }
            }
            mat_barrier(bcnt, bgen, ++phase);   // the single per-round barrier
        }

        // ---- phase C (all blocks, redundant+deterministic): stage cand (tag-
        //      validated), hook into nxt, walk+count fused, swap buffers ----
        for (int i = tid; i < N / 2; i += 1024)             // 16B vector staging
            ((uint4*)scand)[i] = ((const uint4*)gcand)[i];  // quiescent
        __syncthreads();
        for (int c = tid; c < N; c += 1024) {
            int l = cur[c];
            if (l == c) {
                u64 k = scand[c];
                if ((k >> 56) == tg) {                       // fresh this round
                    int v = (int)(k & 0xFFF);
                    int u = (int)((k >> 12) & 0xFFF);
                    int t = cur[v];
                    u64 tk = scand[t];
                    int mutual = 0;
                    if ((tk >> 56) == tg) {
                        int tv = (int)(tk & 0xFFF);
                        mutual = (cur[tv] == c);
                    }
                    if (mutual) {
                        if (c < t) {
                            if (bm == 0) { int idx = atomicAdd(&secnt, 1); ged[idx] = make_int2(u, v); }
                        } else l = t;
                    } else {
                        if (bm == 0) { int idx = atomicAdd(&secnt, 1); ged[idx] = make_int2(u, v); }
                        l = t;
                    }
                }
            }
            nxt[c] = (u16)l;
        }
        __syncthreads();
        int local = 0;
        for (int c = tid; c < N; c += 1024) {   // concurrent root-walk (monotone) + count
            int r = nxt[c];
            int n = nxt[r];
            while (n != r) { r = n; n = nxt[r]; }
            nxt[c] = (u16)r;
            local += (r == c) ? 1 : 0;
        }
        atomicAdd(&sdone[round], local);
        __syncthreads();
        done = (sdone[round] == 1);             // identical across blocks
        { u16* tmp = cur; cur = nxt; nxt = tmp; }
    }

    if (bm == 0) {
        // ============ Euler-tour rooting (leader block, depth-independent) =====
        u32* uvp  = (u32*)SM;                      // 16K @0 (comp buffers dead)
        u16* off  = (u16*)(SM + 16384);            // 8K
        u16* adj  = (u16*)(SM + 24576);            // 16K
        u16* succ = (u16*)(SM + 40960);            // 16K
        u16* rnk  = (u16*)(SM + 16384);            // aliases off+adj (dead)
        u32* minp = (u32*)(SM + 40960);            // aliases succ (dead)

        __syncthreads();
        const int ec = secnt;                      // == N-1
        for (int i = tid; i < ec; i += 1024) {
            int2 e = ged[i];
            uvp[i] = ((u32)e.x << 16) | (u32)e.y;
        }
        for (int i = tid; i < 2048; i += 1024) ((u32*)off)[i] = 0;
        __syncthreads();
        for (int i = tid; i < ec; i += 1024) {
            u32 w = uvp[i];
            int u = (int)(w >> 16), v = (int)(w & 0xFFFF);
            atomicAdd((u32*)off + (u >> 1), 1u << ((u & 1) * 16));
            atomicAdd((u32*)off + (v >> 1), 1u << ((v & 1) * 16));
        }
        __syncthreads();
        {
            const int i0 = tid * 4;
            int d0 = off[i0], d1 = off[i0 + 1], d2 = off[i0 + 2], d3 = off[i0 + 3];
            int t0 = d0, t01 = d0 + d1, t012 = t01 + d2, tot = t012 + d3;
            int inc = tot;
#pragma unroll
            for (int d = 1; d < 64; d <<= 1) {
                int o = __shfl_up(inc, d, 64);
                if (lane >= d) inc += o;
            }
            if (lane == 63) swar[wid] = inc;
            __syncthreads();
            if (wid == 0) {
                int v = (lane < 16) ? swar[lane] : 0;
                int vin = v;
#pragma unroll
                for (int d = 1; d < 16; d <<= 1) {
                    int o = __shfl_up(v, d, 64);
                    if (lane >= d) v += o;
                }
                if (lane < 16) swar[lane] = v - vin;
            }
            __syncthreads();
            int base = swar[wid] + (inc - tot);
            off[i0] = (u16)base;
            off[i0 + 1] = (u16)(base + t0);
            off[i0 + 2] = (u16)(base + t01);
            off[i0 + 3] = (u16)(base + t012);
        }
        __syncthreads();
        for (int e = tid; e < M2; e += 1024) {
            int i = e >> 1;
            u32 w = uvp[i];
            int src = (e & 1) ? (int)(w & 0xFFFF) : (int)(w >> 16);
            u32 old = atomicAdd((u32*)off + (src >> 1), 1u << ((src & 1) * 16));
            u32 slot = (old >> ((src & 1) * 16)) & 0xFFFFu;
            adj[slot] = (u16)e;
            succ[e] = (u16)slot;                 // temp: my slot
        }
        __syncthreads();
        const int e0 = adj[0];                   // first edge out of vertex 0 = tour start
        {
            u16 nsv[8];
            int k = 0;
            for (int e = tid; e < M2; e += 1024) {
                int i = e >> 1;
                u32 w = uvp[i];
                int v = (e & 1) ? (int)(w >> 16) : (int)(w & 0xFFFF);   // dst(e)
                int st = succ[e ^ 1];
                int start = (v == 0) ? 0 : off[v - 1];
                int end = off[v];
                int ns = (st + 1 < end) ? st + 1 : start;
                nsv[k++] = adj[ns];
            }
            __syncthreads();
            k = 0;
            for (int e = tid; e < M2; e += 1024) succ[e] = nsv[k++];
        }
        __syncthreads();
        for (int e = tid; e < M2; e += 1024) {
            u16 s = succ[e];
            if (s == (u16)e0) { succ[e] = (u16)e; rnk[e] = 0; }
            else rnk[e] = 1;
        }
        __syncthreads();
        for (int it = 0; it < 13; ++it) {
            u16 nr[8], s2[8];
            int k = 0;
            for (int e = tid; e < M2; e += 1024) {
                u16 s1 = succ[e];
                u16 r1 = rnk[e];
                nr[k] = (u16)(r1 + rnk[s1]);
                s2[k] = succ[s1];
                ++k;
            }
            __syncthreads();
            k = 0;
            for (int e = tid; e < M2; e += 1024) { rnk[e] = nr[k]; succ[e] = s2[k]; ++k; }
            __syncthreads();
        }
        for (int i = tid; i < N; i += 1024) minp[i] = 0xFFFFFFFFu;
        __syncthreads();
        for (int e = tid; e < M2; e += 1024) {
            int i = e >> 1;
            u32 w = uvp[i];
            int dst = (e & 1) ? (int)(w >> 16) : (int)(w & 0xFFFF);
            int srcv = (e & 1) ? (int)(w & 0xFFFF) : (int)(w >> 16);
            u32 p = (u32)(M2 - 1) - (u32)rnk[e];
            atomicMin(&minp[dst], (p << 16) | (u32)srcv);
        }
        __syncthreads();
        for (int v = tid; v < N; v += 1024) gpar[v] = (v == 0) ? 0 : (int)(minp[v] & 0xFFFFu);
    }

    // ---- global arrive; block 0 waits for all 64, then computes outputs ----
    __syncthreads();
    if (tid == 0) {
        __threadfence();
        atomicAdd(garr, 1);
    }
    if (b != 0) return;
    if (tid == 0) {
        while (__hip_atomic_load(garr, __ATOMIC_ACQUIRE, __HIP_MEMORY_SCOPE_AGENT) < 2 * MBLK)
            __builtin_amdgcn_s_sleep(1);
        __threadfence();
    }
    __syncthreads();

    // fused finalize (block 0 only)
    {
        float* rs12 = (float*)SM;            // tiny scratch
        float* rs21 = (float*)(SM + 64);
        int* rm = (int*)(SM + 128);
        const int* p1 = parent_g;
        const int* p2 = parent_g + N;
        float s12 = 0.f, s21 = 0.f;
        int mcnt = 0;
        for (int c = 1 + tid; c < N; c += 1024) {
            int a = p1[c];
            int bb = p2[c];
            float e1 = D1[(size_t)a * N + c] - D2[(size_t)a * N + c];
            float e2 = D2[(size_t)bb * N + c] - D1[(size_t)bb * N + c];
            s12 += e1 * e1;
            s21 += e2 * e2;
            mcnt += (a == bb) ? 1 : 0;
        }
#pragma unroll
        for (int off = 32; off > 0; off >>= 1) {
            s12 += __shfl_xor(s12, off, 64);
            s21 += __shfl_xor(s21, off, 64);
            mcnt += __shfl_xor(mcnt, off, 64);
        }
        if (lane == 0) { rs12[wid] = s12; rs21[wid] = s21; rm[wid] = mcnt; }
        __syncthreads();
        if (tid == 0) {
            float a = 0.f, bb = 0.f;
            int mm = 0;
#pragma unroll
            for (int w = 0; w < 16; ++w) { a += rs12[w]; bb += rs21[w]; mm += rm[w]; }
            float d12 = sqrtf(a);
            float d21 = sqrtf(bb);
            out[0] = d12 + d21;
            out[1] = d12;
            out[2] = d21;
            out[3] = (float)mm;
        }
    }
}

extern "C" void kernel_launch(void* const* d_in, const int* in_sizes, int n_in,
                              void* d_out, int out_size, void* d_ws, size_t ws_size,
                              hipStream_t stream) {
    const float* D1 = (const float*)d_in[0];
    const float* D2 = (const float*)d_in[1];

    int* parent = WS_PARENT(d_ws);
    int* rcnt = WS_RCNT(d_ws);
    float* rthr = WS_RTHR(d_ws);
    int2* edges = WS_EDGES(d_ws);
    u64* cand = WS_CAND(d_ws);
    int* meta = WS_META(d_ws);
    u64* lists = WS_LISTS(d_ws);

    build_kernel<<<2 * N, 256, 0, stream>>>(D1, D2, rcnt, rthr, lists, cand, meta);
    solve_kernel<<<2 * MBLK, 1024, 0, stream>>>(D1, D2, rcnt, rthr, lists, cand,
                                                edges, parent, meta, (float*)d_out);
}

// Round 8
// 257.881 us; speedup vs baseline: 1.6568x; 1.0718x over previous
//
#include <hip/hip_runtime.h>
#include <math.h>

#define N 4096
#define ROUNDS 12           // round 0 (folded) + 11: components at least halve per hook
#define INFKEY 0xFFFFFFFFFFFFFFFFULL
#define LCAP 64             // candidate-list capacity per row == wave width
#define EC (N - 1)          // MST edge count
#define M2 (2 * EC)         // directed edges (8190)
#define MBLK 32             // blocks per matrix (known-good operating point)
#define RPB (N / MBLK)      // 128 rows per block
#define RPW (RPB / 16)      // 8 rows per wave

typedef unsigned long long u64;
typedef unsigned int u32;
typedef unsigned short u16;
typedef unsigned char u8;

// ---- workspace layout (bytes) ----
#define WS_PARENT(ws) ((int*)((char*)(ws) + 0))          // int[2N]        32 KB
#define WS_RCNT(ws)   ((int*)((char*)(ws) + 32768))      // int[2N]        32 KB
#define WS_RTHR(ws)   ((float*)((char*)(ws) + 65536))    // float[2N]      32 KB
#define WS_EDGES(ws)  ((int2*)((char*)(ws) + 98304))     // int2[2N]       64 KB
#define WS_CAND(ws)   ((u64*)((char*)(ws) + 163840))     // u64[2][2N]    128 KB (double-buffered)
#define WS_META(ws)   ((int*)((char*)(ws) + 294912))     // int[64]
#define WS_LISTS(ws)  ((u64*)((char*)(ws) + 295168))     // u64[2N*LCAP]    4 MB, row-major

// cand key (TAGGED): ((ROUNDS-round) << 56) | (float_bits(w) << 24) | (u << 12) | v
//   Tags strictly decrease per round -> fresh keys always win atomicMin vs
//   stale same-buffer keys; phase C validates tag instead of INFKEY, so no
//   per-round buffer reset and only ONE mat_barrier per round.
// list entry: (float_bits(w) << 12) | j              (44 bits). ORDER IS
//   IRRELEVANT (phase A min-reduces; exhaustion checks all entries), so build
//   emits via atomic position.

// Per-matrix spin barrier over MBLK co-resident blocks (grid 64 on 256 CUs).
__device__ __forceinline__ void mat_barrier(int* cnt, int* gen, int target) {
    __syncthreads();
    if (threadIdx.x == 0) {
        __threadfence();
        int old = atomicAdd(cnt, 1);
        if (old == MBLK - 1) {
            __hip_atomic_store(cnt, 0, __ATOMIC_RELAXED, __HIP_MEMORY_SCOPE_AGENT);
            __hip_atomic_store(gen, target, __ATOMIC_RELEASE, __HIP_MEMORY_SCOPE_AGENT);
        } else {
            while (__hip_atomic_load(gen, __ATOMIC_ACQUIRE, __HIP_MEMORY_SCOPE_AGENT) < target)
                __builtin_amdgcn_s_sleep(1);
        }
        __threadfence();
    }
    __syncthreads();
}

// One 256-thread BLOCK per row (grid 8192). v3: sigma-based one-shot ball
// threshold. Legacy T = mn+0.25*(mean-mn) ~= mean-2.6sigma -> ~19 entries,
// far below LCAP=64 -> early exhaustion -> solve phase-B rescans every round.
// Now: T = mean - 2.25*sigma targets ~50 entries (retry-halving if >64,
// P~2-3%), and emission uses an LDS atomic counter for positions (order
// irrelevant), deleting the count-loop + prefix scans + second emit pass.
__global__ __launch_bounds__(256) void build_kernel(const float* __restrict__ D1,
                                                    const float* __restrict__ D2,
                                                    int* __restrict__ rowcount,
                                                    float* __restrict__ rthresh,
                                                    u64* __restrict__ lists,
                                                    u64* __restrict__ cand,
                                                    int* __restrict__ meta) {
    const int gb = blockIdx.x;   // 8192 blocks: one per (matrix,row)
    const int tid = threadIdx.x;
    const int wid = tid >> 6, lane = tid & 63;

    // folded init: cand buffer 1 (buffer 0 is fully written below) + meta
    if (gb < 8) {
        int i = 2 * N + (gb * 256 + tid) * 4;
        cand[i] = INFKEY; cand[i + 1] = INFKEY; cand[i + 2] = INFKEY; cand[i + 3] = INFKEY;
    } else if (gb == 8 && tid < 64) {
        meta[tid] = 0;
    }

    const int m = gb >> 12;
    const int row = gb & (N - 1);
    const float* __restrict__ Drow = (m ? D2 : D1) + (size_t)row * N;

    __shared__ u64 skmin[4];
    __shared__ float ssum[4];
    __shared__ float ssq[4];
    __shared__ int semit;

    float4 v[4];
#pragma unroll
    for (int it = 0; it < 4; ++it)
        v[it] = *(const float4*)(Drow + it * 1024 + tid * 4);

    // pass 1: per-thread min KEY + sum over 16 elems
    u64 kmin = INFKEY;
    float sm = 0.f;
#pragma unroll
    for (int it = 0; it < 4; ++it) {
        float e4[4] = {v[it].x, v[it].y, v[it].z, v[it].w};
#pragma unroll
        for (int s = 0; s < 4; ++s) {
            float x = e4[s];
            if (x > 0.f) {   // excludes exact-zero diagonal
                u64 k = ((u64)__float_as_uint(x) << 12) | (unsigned)(it * 1024 + tid * 4 + s);
                if (k < kmin) kmin = k;
            }
            sm += x;         // self adds 0, harmless
        }
    }
#pragma unroll
    for (int off = 32; off > 0; off >>= 1) {
        u64 o = __shfl_xor(kmin, off, 64);
        if (o < kmin) kmin = o;
        sm += __shfl_xor(sm, off, 64);
    }
    if (lane == 0) { skmin[wid] = kmin; ssum[wid] = sm; }
    __syncthreads();
    kmin = skmin[0]; sm = ssum[0];
#pragma unroll
    for (int w = 1; w < 4; ++w) {
        if (skmin[w] < kmin) kmin = skmin[w];
        sm += ssum[w];
    }
    const float mn = __uint_as_float((u32)(kmin >> 12));
    const float mean = sm * (1.f / 4095.f);

    // pass 2 (registers): sum of squared deviations -> sigma (two-pass avoids
    // float cancellation; one-pass sumsq has ~2.0 abs error vs var ~0.4)
    float sq = 0.f;
#pragma unroll
    for (int it = 0; it < 4; ++it) {
        float e4[4] = {v[it].x, v[it].y, v[it].z, v[it].w};
#pragma unroll
        for (int s = 0; s < 4; ++s) {
            float x = e4[s];
            if (x > 0.f) { float d = x - mean; sq += d * d; }
        }
    }
#pragma unroll
    for (int off = 32; off > 0; off >>= 1) sq += __shfl_xor(sq, off, 64);
    if (lane == 0) ssq[wid] = sq;
    __syncthreads();
    sq = ssq[0] + ssq[1] + ssq[2] + ssq[3];
    const float sigma = sqrtf(fmaxf(sq * (1.f / 4095.f), 0.f));

    const float gap = mean - mn;
    float T = mean - 2.25f * sigma;          // ~1.2% quantile ~= 50 entries
    const float Tlo = mn + 0.001f * gap;     // guarantee at least the row min
    if (!(T > Tlo)) T = Tlo;                 // also catches NaN

    // emit-with-count loop: atomic positions, retry-halve on overflow (rare)
    u64* lp = lists + ((size_t)m * N + row) * LCAP;   // ROW-major
    int total = 0;
    for (int tries = 0; tries < 8; ++tries) {
        __syncthreads();
        if (tid == 0) semit = 0;
        __syncthreads();
#pragma unroll
        for (int it = 0; it < 4; ++it) {
            float e4[4] = {v[it].x, v[it].y, v[it].z, v[it].w};
#pragma unroll
            for (int s = 0; s < 4; ++s) {
                float x = e4[s];
                if (x > 0.f && x < T) {
                    int p = atomicAdd(&semit, 1);
                    if (p < LCAP)
                        lp[p] = ((u64)__float_as_uint(x) << 12) | (unsigned)(it * 1024 + tid * 4 + s);
                }
            }
        }
        __syncthreads();
        total = semit;                        // block-uniform
        if (total <= LCAP) break;             // uniform break
        T = mn + 0.5f * (T - mn);
    }

    if (tid == 0) {
        rowcount[m * N + row] = total;
        rthresh[m * N + row] = T;
        // Boruvka round-0 candidate, tag = ROUNDS, unique writer per row
        cand[m * N + row] = ((u64)ROUNDS << 56) | ((kmin >> 12) << 24) | ((u64)row << 12) | (kmin & 0xFFF);
    }
}

// 32 blocks per matrix (64 total). Round 0 = hook only. Rounds 1+:
// A (list scan + flush) -> B (bound filter + rare rescans, NO barrier before)
// -> mat_barrier -> C (redundant deterministic hook+compress). Verified at
// 276.4 us total (round 7); unchanged this round.
__global__ __launch_bounds__(1024) void solve_kernel(const float* __restrict__ D1,
                                                     const float* __restrict__ D2,
                                                     const int* __restrict__ rcnt,
                                                     const float* __restrict__ rthr,
                                                     const u64* __restrict__ lists,
                                                     u64* __restrict__ cand_g,
                                                     int2* __restrict__ edges_g,
                                                     int* __restrict__ parent_g,
                                                     int* __restrict__ meta,
                                                     float* __restrict__ out) {
    const int b = blockIdx.x;
    const int m = b / MBLK;
    const int bm = b - m * MBLK;
    const int tid = threadIdx.x;
    const int wid = tid >> 6, lane = tid & 63;
    const float* __restrict__ D = m ? D2 : D1;
    const int* __restrict__ grc = rcnt + m * N;
    const float* __restrict__ gth = rthr + m * N;
    const u64* __restrict__ gls = lists + (size_t)m * N * LCAP;
    int2* __restrict__ ged = edges_g + (size_t)m * N;
    int* __restrict__ gpar = parent_g + m * N;
    int* bcnt = meta + m * 16 + 1;
    int* bgen = meta + m * 16 + 2;
    int* garr = meta + 40;                 // global arrive counter (all 64 blocks)
    const float INF = __builtin_inff();

    __shared__ __align__(16) char SM[57344];   // 56 KB arena, phase-aliased
    u16* comp0 = (u16*)SM;                     // 8 KB @0    (component buffer A)
    u16* comp1 = (u16*)(SM + 8192);            // 8 KB @8K   (component buffer B)
    u64* scand = (u64*)(SM + 16384);           // 32 KB @16K (local min mirror / staged cand)
    u16* sresc = (u16*)(SM + 49152);           // 8 KB  @48K (rescan list)
    __shared__ u8 sexh[RPB];                   // monotone exhausted-row flags
    __shared__ int snres, secnt, sdone[ROUNDS], swar[16];

    u16* cur = comp0;                          // swapped identically in all threads
    u16* nxt = comp1;

    for (int i = tid; i < N; i += 1024) cur[i] = (u16)i;
    for (int i = tid; i < RPB; i += 1024) sexh[i] = 0;
    if (tid == 0) secnt = 0;
    if (tid < ROUNDS) sdone[tid] = 0;
    int phase = 0;
    bool done = false;

    for (int round = 0; round < ROUNDS && !done; ++round) {
        const int buf = round & 1;
        const u64 tg = (u64)(ROUNDS - round);          // this round's tag
        const u64 tgs = tg << 56;
        u64* __restrict__ gcand = cand_g + (size_t)buf * 2 * N + m * N;

        if (round > 0) {
            for (int i = tid; i < N; i += 1024) scand[i] = INFKEY;
            if (tid == 0) snres = 0;
            __syncthreads();

            // ---- phase A: prefetched list scan; exhausted rows skip ----
            {
                const int lbase = wid * RPW;
                int cnts[RPW];
                u64 ent[RPW];
#pragma unroll
                for (int r = 0; r < RPW; ++r) {
                    int lrow = lbase + r;
                    cnts[r] = sexh[lrow] ? -1 : grc[bm * RPB + lrow];   // uniform scalar load
                }
#pragma unroll
                for (int r = 0; r < RPW; ++r) {   // 8 independent global loads in flight
                    int lrow = lbase + r;
                    ent[r] = (cnts[r] > lane) ? gls[(size_t)(bm * RPB + lrow) * LCAP + lane]
                                              : INFKEY;
                }
#pragma unroll
                for (int r = 0; r < RPW; ++r) {
                    const int lrow = lbase + r;
                    const int row = bm * RPB + lrow;
                    if (cnts[r] < 0) {                       // known exhausted
                        if (lane == 0) { int i = atomicAdd(&snres, 1); sresc[i] = (u16)(row | 0x1000); }
                        continue;
                    }
                    if (cnts[r] > LCAP) {                    // defensive overflow
                        if (lane == 0) { int i = atomicAdd(&snres, 1); sresc[i] = (u16)(row | 0x4000); }
                        continue;
                    }
                    const int c = cur[row];
                    u64 e = ent[r];
                    u64 best = (e != INFKEY && cur[(int)(e & 0xFFF)] != c) ? e : INFKEY;
#pragma unroll
                    for (int off = 32; off > 0; off >>= 1) {
                        u64 o = __shfl_xor(best, off, 64);
                        if (o < best) best = o;
                    }
                    if (lane == 0) {
                        if (best != INFKEY) {
                            u64 key = tgs | ((best >> 12) << 24) | ((u64)row << 12) | (best & 0xFFF);
                            if (key < scand[c]) atomicMin(&scand[c], key);
                        } else {
                            sexh[lrow] = 1;                  // permanent (monotone)
                            int i = atomicAdd(&snres, 1); sresc[i] = (u16)(row | 0x1000);
                        }
                    }
                }
            }
            __syncthreads();
            for (int c = tid; c < N; c += 1024) {            // flush block-local mins
                u64 v = scand[c];
                if (v != INFKEY) atomicMin(&gcand[c], v);
            }
            __syncthreads();                 // own flushes visible to own filter reads

            // ---- phase B (no preceding barrier): bound filter; rare rescans ----
            for (int i = tid; i < snres; i += 1024) {
                u16 e = sresc[i];
                if (e & 0x1000) {
                    int row = e & 0xFFF;
                    int c = cur[row];
                    u64 cc = gcand[c];           // partial/monotone: skip stays safe
                    float w = ((cc >> 56) == tg) ? __uint_as_float((u32)(cc >> 24)) : INF;
                    if (!(gth[row] < w)) sresc[i] = 0xFFFF;
                }
            }
            __syncthreads();
            {
                const int nres = snres;
                for (int i = wid; i < nres; i += 16) {
                    u16 e = sresc[i];            // wave-uniform broadcast
                    if (e == 0xFFFF) continue;
                    int row = (int)(e & 0xFFF);
                    int c = cur[row];
                    const float* Drow = D + (size_t)row * N;
                    u64 best = INFKEY;
                    for (int j0 = lane * 4; j0 < N; j0 += 256) {
                        float4 d = *(const float4*)(Drow + j0);
                        ushort4 cj = *(const ushort4*)(cur + j0);
                        if (cj.x != c) { u64 k = ((u64)__float_as_uint(d.x) << 12) | (unsigned)(j0 + 0); if (k < best) best = k; }
                        if (cj.y != c) { u64 k = ((u64)__float_as_uint(d.y) << 12) | (unsigned)(j0 + 1); if (k < best) best = k; }
                        if (cj.z != c) { u64 k = ((u64)__float_as_uint(d.z) << 12) | (unsigned)(j0 + 2); if (k < best) best = k; }
                        if (cj.w != c) { u64 k = ((u64)__float_as_uint(d.w) << 12) | (unsigned)(j0 + 3); if (k < best) best = k; }
                    }
#pragma unroll
                    for (int off = 32; off > 0; off >>= 1) {
                        u64 o = __shfl_xor(best, off, 64);
                        if (o < best) best = o;
                    }
                    if (lane == 0 && best != INFKEY) {
                        u64 key = tgs | ((best >> 12) << 24) | ((u64)row << 12) | (best & 0xFFF);
                        atomicMin(&gcand[c], key);
                    }
                }
            }
            mat_barrier(bcnt, bgen, ++phase);   // the single per-round barrier
        }

        // ---- phase C (all blocks, redundant+deterministic): stage cand (tag-
        //      validated), hook into nxt, walk+count fused, swap buffers ----
        for (int i = tid; i < N / 2; i += 1024)             // 16B vector staging
            ((uint4*)scand)[i] = ((const uint4*)gcand)[i];  // quiescent
        __syncthreads();
        for (int c = tid; c < N; c += 1024) {
            int l = cur[c];
            if (l == c) {
                u64 k = scand[c];
                if ((k >> 56) == tg) {                       // fresh this round
                    int v = (int)(k & 0xFFF);
                    int u = (int)((k >> 12) & 0xFFF);
                    int t = cur[v];
                    u64 tk = scand[t];
                    int mutual = 0;
                    if ((tk >> 56) == tg) {
                        int tv = (int)(tk & 0xFFF);
                        mutual = (cur[tv] == c);
                    }
                    if (mutual) {
                        if (c < t) {
                            if (bm == 0) { int idx = atomicAdd(&secnt, 1); ged[idx] = make_int2(u, v); }
                        } else l = t;
                    } else {
                        if (bm == 0) { int idx = atomicAdd(&secnt, 1); ged[idx] = make_int2(u, v); }
                        l = t;
                    }
                }
            }
            nxt[c] = (u16)l;
        }
        __syncthreads();
        int local = 0;
        for (int c = tid; c < N; c += 1024) {   // concurrent root-walk (monotone) + count
            int r = nxt[c];
            int n = nxt[r];
            while (n != r) { r = n; n = nxt[r]; }
            nxt[c] = (u16)r;
            local += (r == c) ? 1 : 0;
        }
        atomicAdd(&sdone[round], local);
        __syncthreads();
        done = (sdone[round] == 1);             // identical across blocks
        { u16* tmp = cur; cur = nxt; nxt = tmp; }
    }

    if (bm == 0) {
        // ============ Euler-tour rooting (leader block, depth-independent) =====
        u32* uvp  = (u32*)SM;                      // 16K @0 (comp buffers dead)
        u16* off  = (u16*)(SM + 16384);            // 8K
        u16* adj  = (u16*)(SM + 24576);            // 16K
        u16* succ = (u16*)(SM + 40960);            // 16K
        u16* rnk  = (u16*)(SM + 16384);            // aliases off+adj (dead)
        u32* minp = (u32*)(SM + 40960);            // aliases succ (dead)

        __syncthreads();
        const int ec = secnt;                      // == N-1
        for (int i = tid; i < ec; i += 1024) {
            int2 e = ged[i];
            uvp[i] = ((u32)e.x << 16) | (u32)e.y;
        }
        for (int i = tid; i < 2048; i += 1024) ((u32*)off)[i] = 0;
        __syncthreads();
        for (int i = tid; i < ec; i += 1024) {
            u32 w = uvp[i];
            int u = (int)(w >> 16), v = (int)(w & 0xFFFF);
            atomicAdd((u32*)off + (u >> 1), 1u << ((u & 1) * 16));
            atomicAdd((u32*)off + (v >> 1), 1u << ((v & 1) * 16));
        }
        __syncthreads();
        {
            const int i0 = tid * 4;
            int d0 = off[i0], d1 = off[i0 + 1], d2 = off[i0 + 2], d3 = off[i0 + 3];
            int t0 = d0, t01 = d0 + d1, t012 = t01 + d2, tot = t012 + d3;
            int inc = tot;
#pragma unroll
            for (int d = 1; d < 64; d <<= 1) {
                int o = __shfl_up(inc, d, 64);
                if (lane >= d) inc += o;
            }
            if (lane == 63) swar[wid] = inc;
            __syncthreads();
            if (wid == 0) {
                int v = (lane < 16) ? swar[lane] : 0;
                int vin = v;
#pragma unroll
                for (int d = 1; d < 16; d <<= 1) {
                    int o = __shfl_up(v, d, 64);
                    if (lane >= d) v += o;
                }
                if (lane < 16) swar[lane] = v - vin;
            }
            __syncthreads();
            int base = swar[wid] + (inc - tot);
            off[i0] = (u16)base;
            off[i0 + 1] = (u16)(base + t0);
            off[i0 + 2] = (u16)(base + t01);
            off[i0 + 3] = (u16)(base + t012);
        }
        __syncthreads();
        for (int e = tid; e < M2; e += 1024) {
            int i = e >> 1;
            u32 w = uvp[i];
            int src = (e & 1) ? (int)(w & 0xFFFF) : (int)(w >> 16);
            u32 old = atomicAdd((u32*)off + (src >> 1), 1u << ((src & 1) * 16));
            u32 slot = (old >> ((src & 1) * 16)) & 0xFFFFu;
            adj[slot] = (u16)e;
            succ[e] = (u16)slot;                 // temp: my slot
        }
        __syncthreads();
        const int e0 = adj[0];                   // first edge out of vertex 0 = tour start
        {
            u16 nsv[8];
            int k = 0;
            for (int e = tid; e < M2; e += 1024) {
                int i = e >> 1;
                u32 w = uvp[i];
                int v = (e & 1) ? (int)(w >> 16) : (int)(w & 0xFFFF);   // dst(e)
                int st = succ[e ^ 1];
                int start = (v == 0) ? 0 : off[v - 1];
                int end = off[v];
                int ns = (st + 1 < end) ? st + 1 : start;
                nsv[k++] = adj[ns];
            }
            __syncthreads();
            k = 0;
            for (int e = tid; e < M2; e += 1024) succ[e] = nsv[k++];
        }
        __syncthreads();
        for (int e = tid; e < M2; e += 1024) {
            u16 s = succ[e];
            if (s == (u16)e0) { succ[e] = (u16)e; rnk[e] = 0; }
            else rnk[e] = 1;
        }
        __syncthreads();
        for (int it = 0; it < 13; ++it) {
            u16 nr[8], s2[8];
            int k = 0;
            for (int e = tid; e < M2; e += 1024) {
                u16 s1 = succ[e];
                u16 r1 = rnk[e];
                nr[k] = (u16)(r1 + rnk[s1]);
                s2[k] = succ[s1];
                ++k;
            }
            __syncthreads();
            k = 0;
            for (int e = tid; e < M2; e += 1024) { rnk[e] = nr[k]; succ[e] = s2[k]; ++k; }
            __syncthreads();
        }
        for (int i = tid; i < N; i += 1024) minp[i] = 0xFFFFFFFFu;
        __syncthreads();
        for (int e = tid; e < M2; e += 1024) {
            int i = e >> 1;
            u32 w = uvp[i];
            int dst = (e & 1) ? (int)(w >> 16) : (int)(w & 0xFFFF);
            int srcv = (e & 1) ? (int)(w & 0xFFFF) : (int)(w >> 16);
            u32 p = (u32)(M2 - 1) - (u32)rnk[e];
            atomicMin(&minp[dst], (p << 16) | (u32)srcv);
        }
        __syncthreads();
        for (int v = tid; v < N; v += 1024) gpar[v] = (v == 0) ? 0 : (int)(minp[v] & 0xFFFFu);
    }

    // ---- global arrive; block 0 waits for all 64, then computes outputs ----
    __syncthreads();
    if (tid == 0) {
        __threadfence();
        atomicAdd(garr, 1);
    }
    if (b != 0) return;
    if (tid == 0) {
        while (__hip_atomic_load(garr, __ATOMIC_ACQUIRE, __HIP_MEMORY_SCOPE_AGENT) < 2 * MBLK)
            __builtin_amdgcn_s_sleep(1);
        __threadfence();
    }
    __syncthreads();

    // fused finalize (block 0 only)
    {
        float* rs12 = (float*)SM;            // tiny scratch
        float* rs21 = (float*)(SM + 64);
        int* rm = (int*)(SM + 128);
        const int* p1 = parent_g;
        const int* p2 = parent_g + N;
        float s12 = 0.f, s21 = 0.f;
        int mcnt = 0;
        for (int c = 1 + tid; c < N; c += 1024) {
            int a = p1[c];
            int bb = p2[c];
            float e1 = D1[(size_t)a * N + c] - D2[(size_t)a * N + c];
            float e2 = D2[(size_t)bb * N + c] - D1[(size_t)bb * N + c];
            s12 += e1 * e1;
            s21 += e2 * e2;
            mcnt += (a == bb) ? 1 : 0;
        }
#pragma unroll
        for (int off = 32; off > 0; off >>= 1) {
            s12 += __shfl_xor(s12, off, 64);
            s21 += __shfl_xor(s21, off, 64);
            mcnt += __shfl_xor(mcnt, off, 64);
        }
        if (lane == 0) { rs12[wid] = s12; rs21[wid] = s21; rm[wid] = mcnt; }
        __syncthreads();
        if (tid == 0) {
            float a = 0.f, bb = 0.f;
            int mm = 0;
#pragma unroll
            for (int w = 0; w < 16; ++w) { a += rs12[w]; bb += rs21[w]; mm += rm[w]; }
            float d12 = sqrtf(a);
            float d21 = sqrtf(bb);
            out[0] = d12 + d21;
            out[1] = d12;
            out[2] = d21;
            out[3] = (float)mm;
        }
    }
}

extern "C" void kernel_launch(void* const* d_in, const int* in_sizes, int n_in,
                              void* d_out, int out_size, void* d_ws, size_t ws_size,
                              hipStream_t stream) {
    const float* D1 = (const float*)d_in[0];
    const float* D2 = (const float*)d_in[1];

    int* parent = WS_PARENT(d_ws);
    int* rcnt = WS_RCNT(d_ws);
    float* rthr = WS_RTHR(d_ws);
    int2* edges = WS_EDGES(d_ws);
    u64* cand = WS_CAND(d_ws);
    int* meta = WS_META(d_ws);
    u64* lists = WS_LISTS(d_ws);

    build_kernel<<<2 * N, 256, 0, stream>>>(D1, D2, rcnt, rthr, lists, cand, meta);
    solve_kernel<<<2 * MBLK, 1024, 0, stream>>>(D1, D2, rcnt, rthr, lists, cand,
                                                edges, parent, meta, (float*)d_out);
}